// Round 1
// baseline (16003.119 us; speedup 1.0000x reference)
//
#include <hip/hip_runtime.h>
#include <hip/hip_bf16.h>
#include <math.h>

#define DIM 768
#define LAYERS 12
#define NH 12
#define HDIM 64
#define FFDIM 3072
#define SEQ 256
#define BATCH 8
#define MTOK (BATCH*SEQ)   // 2048
#define TASKS 3
#define LRANK 16
#define LORA_SC 2.0f

__device__ __forceinline__ float geluf(float x) {
    float x3 = x * x * x;
    return 0.5f * x * (1.0f + tanhf(0.7978845608028654f * (x + 0.044715f * x3)));
}

__device__ __forceinline__ float block_sum256(float v, volatile float* sb4) {
    #pragma unroll
    for (int o = 32; o; o >>= 1) v += __shfl_down(v, o);
    int w = threadIdx.x >> 6;
    if ((threadIdx.x & 63) == 0) sb4[w] = v;
    __syncthreads();
    float total = sb4[0] + sb4[1] + sb4[2] + sb4[3];
    __syncthreads();
    return total;
}

// ---------------- embedding + LN ----------------
__global__ __launch_bounds__(256) void embed_ln_kernel(
    const int* __restrict__ ids, const float* __restrict__ wemb,
    const float* __restrict__ pemb, const float* __restrict__ g,
    const float* __restrict__ bb, float* __restrict__ out) {
    __shared__ float sb[4];
    int m = blockIdx.x;
    int s = m & (SEQ - 1);
    int id = ids[m];
    int t = threadIdx.x;
    float x[3];
    float sum = 0.f;
    #pragma unroll
    for (int j = 0; j < 3; ++j) {
        int d = t + j * 256;
        x[j] = wemb[(size_t)id * DIM + d] + pemb[(size_t)(s + 2) * DIM + d];
        sum += x[j];
    }
    float mean = block_sum256(sum, sb) * (1.0f / DIM);
    float vs = 0.f;
    #pragma unroll
    for (int j = 0; j < 3; ++j) { float c = x[j] - mean; vs += c * c; }
    float var = block_sum256(vs, sb) * (1.0f / DIM);
    float rstd = rsqrtf(var + 1e-5f);
    #pragma unroll
    for (int j = 0; j < 3; ++j) {
        int d = t + j * 256;
        out[(size_t)m * DIM + d] = (x[j] - mean) * rstd * g[d] + bb[d];
    }
}

// ---------------- residual add + LN (in-place on h) ----------------
__global__ __launch_bounds__(256) void add_ln_kernel(
    float* __restrict__ h, const float* __restrict__ proj,
    const float* __restrict__ g, const float* __restrict__ bb) {
    __shared__ float sb[4];
    int m = blockIdx.x;
    int t = threadIdx.x;
    float x[3];
    float sum = 0.f;
    #pragma unroll
    for (int j = 0; j < 3; ++j) {
        int d = t + j * 256;
        x[j] = h[(size_t)m * DIM + d] + proj[(size_t)m * DIM + d];
        sum += x[j];
    }
    float mean = block_sum256(sum, sb) * (1.0f / DIM);
    float vs = 0.f;
    #pragma unroll
    for (int j = 0; j < 3; ++j) { float c = x[j] - mean; vs += c * c; }
    float var = block_sum256(vs, sb) * (1.0f / DIM);
    float rstd = rsqrtf(var + 1e-5f);
    #pragma unroll
    for (int j = 0; j < 3; ++j) {
        int d = t + j * 256;
        h[(size_t)m * DIM + d] = (x[j] - mean) * rstd * g[d] + bb[d];
    }
}

// ---------------- tiled fp32 GEMM: C = A@W + bias, optional GELU ----------------
// A: MxK row-major, W: KxN row-major. 64x64 tile, BK=16, 4x4 per thread.
template<int ACT>
__global__ __launch_bounds__(256) void gemm_bias_kernel(
    const float* __restrict__ A, const float* __restrict__ W,
    const float* __restrict__ bias, float* __restrict__ C,
    int M, int N, int K) {
    __shared__ float As[16][64];   // [k][m]
    __shared__ float Bs[16][64];   // [k][n]
    int t = threadIdx.x;
    int tx = t & 15, ty = t >> 4;
    int m0 = blockIdx.y * 64;
    int n0 = blockIdx.x * 64;
    float acc[4][4];
    #pragma unroll
    for (int i = 0; i < 4; ++i)
        #pragma unroll
        for (int j = 0; j < 4; ++j) acc[i][j] = 0.f;

    int arow = t >> 2, akg = t & 3;
    int brow = t >> 4, bcol = (t & 15) * 4;
    const float* Aptr = A + (size_t)(m0 + arow) * K + akg * 4;
    const float* Wptr = W + (size_t)brow * N + n0 + bcol;

    for (int k0 = 0; k0 < K; k0 += 16) {
        float4 av = *(const float4*)(Aptr + k0);
        float4 wv = *(const float4*)(Wptr + (size_t)k0 * N);
        As[akg * 4 + 0][arow] = av.x;
        As[akg * 4 + 1][arow] = av.y;
        As[akg * 4 + 2][arow] = av.z;
        As[akg * 4 + 3][arow] = av.w;
        *(float4*)&Bs[brow][bcol] = wv;
        __syncthreads();
        #pragma unroll
        for (int kk = 0; kk < 16; ++kk) {
            float4 a = *(const float4*)&As[kk][ty * 4];
            float4 b = *(const float4*)&Bs[kk][tx * 4];
            float avv[4] = {a.x, a.y, a.z, a.w};
            float bvv[4] = {b.x, b.y, b.z, b.w};
            #pragma unroll
            for (int i = 0; i < 4; ++i)
                #pragma unroll
                for (int j = 0; j < 4; ++j)
                    acc[i][j] += avv[i] * bvv[j];
        }
        __syncthreads();
    }
    #pragma unroll
    for (int i = 0; i < 4; ++i) {
        int mr = m0 + ty * 4 + i;
        #pragma unroll
        for (int j = 0; j < 4; ++j) {
            int nc = n0 + tx * 4 + j;
            float r = acc[i][j] + bias[nc];
            if (ACT == 1) r = geluf(r);
            C[(size_t)mr * N + nc] = r;
        }
    }
}

// ---------------- attention scores: S = Q@K^T (raw dots) ----------------
__global__ __launch_bounds__(256) void attn_scores_kernel(
    const float* __restrict__ qb, const float* __restrict__ kb,
    float* __restrict__ scores) {
    int kt = blockIdx.x, qt = blockIdx.y, bh = blockIdx.z;
    int b = bh / NH, h = bh % NH;
    __shared__ float Qs[64][64];   // [d][q]
    __shared__ float Ks[64][64];   // [d][k]
    int t = threadIdx.x;
    int tx = t & 15, ty = t >> 4;
    #pragma unroll
    for (int it = 0; it < 4; ++it) {
        int idx = it * 256 + t;
        int row = idx >> 4, cg = idx & 15;
        float4 qv = *(const float4*)&qb[(size_t)(b * SEQ + qt * 64 + row) * DIM + h * HDIM + cg * 4];
        Qs[cg * 4 + 0][row] = qv.x; Qs[cg * 4 + 1][row] = qv.y;
        Qs[cg * 4 + 2][row] = qv.z; Qs[cg * 4 + 3][row] = qv.w;
        float4 kv = *(const float4*)&kb[(size_t)(b * SEQ + kt * 64 + row) * DIM + h * HDIM + cg * 4];
        Ks[cg * 4 + 0][row] = kv.x; Ks[cg * 4 + 1][row] = kv.y;
        Ks[cg * 4 + 2][row] = kv.z; Ks[cg * 4 + 3][row] = kv.w;
    }
    __syncthreads();
    float acc[4][4];
    #pragma unroll
    for (int i = 0; i < 4; ++i)
        #pragma unroll
        for (int j = 0; j < 4; ++j) acc[i][j] = 0.f;
    #pragma unroll 4
    for (int kk = 0; kk < 64; ++kk) {
        float4 a = *(const float4*)&Qs[kk][ty * 4];
        float4 b2 = *(const float4*)&Ks[kk][tx * 4];
        float avv[4] = {a.x, a.y, a.z, a.w};
        float bvv[4] = {b2.x, b2.y, b2.z, b2.w};
        #pragma unroll
        for (int i = 0; i < 4; ++i)
            #pragma unroll
            for (int j = 0; j < 4; ++j)
                acc[i][j] += avv[i] * bvv[j];
    }
    #pragma unroll
    for (int i = 0; i < 4; ++i)
        #pragma unroll
        for (int j = 0; j < 4; ++j)
            scores[((size_t)bh * SEQ + qt * 64 + ty * 4 + i) * SEQ + kt * 64 + tx * 4 + j] = acc[i][j];
}

// ---------------- softmax with scale + mask bias, in place ----------------
__global__ __launch_bounds__(256) void softmax_kernel(
    float* __restrict__ scores, const int* __restrict__ mask) {
    int wave = threadIdx.x >> 6, lane = threadIdx.x & 63;
    int g = blockIdx.x * 4 + wave;
    int b = g / (NH * SEQ);
    float* row = scores + (size_t)g * SEQ;
    float s[4];
    float m = -1e30f;
    #pragma unroll
    for (int j = 0; j < 4; ++j) {
        int k = j * 64 + lane;
        float mb = (1.0f - (float)mask[b * SEQ + k]) * -1e9f;
        s[j] = row[k] * 0.125f + mb;
        m = fmaxf(m, s[j]);
    }
    #pragma unroll
    for (int o = 32; o; o >>= 1) m = fmaxf(m, __shfl_xor(m, o));
    float sum = 0.f;
    #pragma unroll
    for (int j = 0; j < 4; ++j) { s[j] = __expf(s[j] - m); sum += s[j]; }
    #pragma unroll
    for (int o = 32; o; o >>= 1) sum += __shfl_xor(sum, o);
    float inv = 1.0f / sum;
    #pragma unroll
    for (int j = 0; j < 4; ++j) row[j * 64 + lane] = s[j] * inv;
}

// ---------------- attention PV: O = att@V ----------------
__global__ __launch_bounds__(256) void attn_pv_kernel(
    const float* __restrict__ scores, const float* __restrict__ vb,
    float* __restrict__ o) {
    int qt = blockIdx.x, bh = blockIdx.y;
    int b = bh / NH, h = bh % NH;
    __shared__ float Ps[64][64];   // [k][q]
    __shared__ float Vs[64][64];   // [k][d]
    int t = threadIdx.x;
    int tx = t & 15, ty = t >> 4;
    float acc[4][4];
    #pragma unroll
    for (int i = 0; i < 4; ++i)
        #pragma unroll
        for (int j = 0; j < 4; ++j) acc[i][j] = 0.f;
    for (int k0 = 0; k0 < SEQ; k0 += 64) {
        #pragma unroll
        for (int it = 0; it < 4; ++it) {
            int idx = it * 256 + t;
            int row = idx >> 4, cg = idx & 15;
            float4 pv = *(const float4*)&scores[((size_t)bh * SEQ + qt * 64 + row) * SEQ + k0 + cg * 4];
            Ps[cg * 4 + 0][row] = pv.x; Ps[cg * 4 + 1][row] = pv.y;
            Ps[cg * 4 + 2][row] = pv.z; Ps[cg * 4 + 3][row] = pv.w;
            float4 vv = *(const float4*)&vb[(size_t)(b * SEQ + k0 + row) * DIM + h * HDIM + cg * 4];
            *(float4*)&Vs[row][cg * 4] = vv;
        }
        __syncthreads();
        #pragma unroll 4
        for (int kk = 0; kk < 64; ++kk) {
            float4 a = *(const float4*)&Ps[kk][ty * 4];
            float4 b2 = *(const float4*)&Vs[kk][tx * 4];
            float avv[4] = {a.x, a.y, a.z, a.w};
            float bvv[4] = {b2.x, b2.y, b2.z, b2.w};
            #pragma unroll
            for (int i = 0; i < 4; ++i)
                #pragma unroll
                for (int j = 0; j < 4; ++j)
                    acc[i][j] += avv[i] * bvv[j];
        }
        __syncthreads();
    }
    #pragma unroll
    for (int i = 0; i < 4; ++i)
        #pragma unroll
        for (int j = 0; j < 4; ++j)
            o[(size_t)(b * SEQ + qt * 64 + ty * 4 + i) * DIM + h * HDIM + tx * 4 + j] = acc[i][j];
}

// ---------------- LoRA: q += 2 * (h @ A^T) @ B^T, per 64-row block ----------------
__global__ __launch_bounds__(256) void lora_add_kernel(
    const float* __restrict__ h, const float* __restrict__ Abase,
    const float* __restrict__ Bbase, const int* __restrict__ task,
    int layer, float* __restrict__ q) {
    int m0 = blockIdx.x * 64;
    int b = m0 >> 8;
    int tk = task[b];
    const float* Ap = Abase + (size_t)(tk * LAYERS + layer) * LRANK * DIM; // (R,D)
    const float* Bp = Bbase + (size_t)(tk * LAYERS + layer) * DIM * LRANK; // (D,R)
    __shared__ float tmp[64][16];
    int t = threadIdx.x;
    int row = t & 63, rb = t >> 6;
    float s[4] = {0.f, 0.f, 0.f, 0.f};
    const float* hrow = h + (size_t)(m0 + row) * DIM;
    for (int d = 0; d < DIM; d += 4) {
        float4 hv = *(const float4*)&hrow[d];
        #pragma unroll
        for (int i = 0; i < 4; ++i) {
            float4 av = *(const float4*)&Ap[(size_t)(rb + i * 4) * DIM + d];
            s[i] += hv.x * av.x + hv.y * av.y + hv.z * av.z + hv.w * av.w;
        }
    }
    #pragma unroll
    for (int i = 0; i < 4; ++i) tmp[row][rb + i * 4] = s[i];
    __syncthreads();
    float qbr[3][16];
    #pragma unroll
    for (int c = 0; c < 3; ++c)
        #pragma unroll
        for (int r4 = 0; r4 < 4; ++r4)
            *(float4*)&qbr[c][r4 * 4] = *(const float4*)&Bp[(size_t)(t * 3 + c) * LRANK + r4 * 4];
    for (int rr = 0; rr < 64; ++rr) {
        float a0 = 0.f, a1 = 0.f, a2 = 0.f;
        #pragma unroll
        for (int r = 0; r < 16; ++r) {
            float tv = tmp[rr][r];
            a0 += tv * qbr[0][r];
            a1 += tv * qbr[1][r];
            a2 += tv * qbr[2][r];
        }
        float* qrow = q + (size_t)(m0 + rr) * DIM + t * 3;
        qrow[0] += LORA_SC * a0;
        qrow[1] += LORA_SC * a1;
        qrow[2] += LORA_SC * a2;
    }
}

// ---------------- router head ----------------
__global__ __launch_bounds__(256) void router_kernel(
    const float* __restrict__ hb, const float* __restrict__ W1,
    const float* __restrict__ b1, const float* __restrict__ W2,
    const float* __restrict__ b2, const float* __restrict__ temp,
    float* __restrict__ out_logits, int* __restrict__ task) {
    int b = blockIdx.x;
    int t = threadIdx.x;
    __shared__ float cls[DIM];
    __shared__ float y1[DIM];
    __shared__ float red[3][4];
    #pragma unroll
    for (int j = 0; j < 3; ++j) cls[t + j * 256] = hb[(size_t)(b * SEQ) * DIM + t + j * 256];
    __syncthreads();
    #pragma unroll
    for (int j = 0; j < 3; ++j) {
        int col = t + j * 256;
        float s = b1[col];
        for (int d = 0; d < DIM; ++d) s += cls[d] * W1[(size_t)d * DIM + col];
        y1[col] = fmaxf(s, 0.0f);
    }
    __syncthreads();
    float p[3] = {0.f, 0.f, 0.f};
    #pragma unroll
    for (int j = 0; j < 3; ++j) {
        int col = t + j * 256;
        float y = y1[col];
        p[0] += y * W2[col * 3 + 0];
        p[1] += y * W2[col * 3 + 1];
        p[2] += y * W2[col * 3 + 2];
    }
    #pragma unroll
    for (int o = 32; o; o >>= 1) {
        p[0] += __shfl_down(p[0], o);
        p[1] += __shfl_down(p[1], o);
        p[2] += __shfl_down(p[2], o);
    }
    int w = t >> 6;
    if ((t & 63) == 0) { red[0][w] = p[0]; red[1][w] = p[1]; red[2][w] = p[2]; }
    __syncthreads();
    if (t == 0) {
        float tt = fmaxf(temp[0], 0.05f);
        float l[3];
        #pragma unroll
        for (int c = 0; c < 3; ++c) {
            l[c] = (red[c][0] + red[c][1] + red[c][2] + red[c][3] + b2[c]) / tt;
            out_logits[b * 3 + c] = l[c];
        }
        int bt = 0; float bv = l[0];
        if (l[1] > bv) { bv = l[1]; bt = 1; }
        if (l[2] > bv) { bv = l[2]; bt = 2; }
        task[b] = bt;
    }
}

// ---------------- final classifier head ----------------
__global__ __launch_bounds__(256) void cls_kernel(
    const float* __restrict__ ha, const float* __restrict__ cW1,
    const float* __restrict__ cb1, const float* __restrict__ cW2,
    const float* __restrict__ cb2, const int* __restrict__ task,
    float* __restrict__ out) {
    int b = blockIdx.x;
    int t = threadIdx.x;
    int tk = task[b];
    const float* W1 = cW1 + (size_t)tk * DIM * DIM;
    const float* b1 = cb1 + tk * DIM;
    const float* W2 = cW2 + (size_t)tk * DIM * 2;
    const float* b2 = cb2 + tk * 2;
    __shared__ float f[DIM];
    __shared__ float y1[DIM];
    __shared__ float red[2][4];
    #pragma unroll
    for (int j = 0; j < 3; ++j) f[t + j * 256] = ha[(size_t)(b * SEQ) * DIM + t + j * 256];
    __syncthreads();
    #pragma unroll
    for (int j = 0; j < 3; ++j) {
        int col = t + j * 256;
        float s = b1[col];
        for (int d = 0; d < DIM; ++d) s += f[d] * W1[(size_t)d * DIM + col];
        y1[col] = tanhf(s);
    }
    __syncthreads();
    float p[2] = {0.f, 0.f};
    #pragma unroll
    for (int j = 0; j < 3; ++j) {
        int col = t + j * 256;
        float y = y1[col];
        p[0] += y * W2[col * 2 + 0];
        p[1] += y * W2[col * 2 + 1];
    }
    #pragma unroll
    for (int o = 32; o; o >>= 1) {
        p[0] += __shfl_down(p[0], o);
        p[1] += __shfl_down(p[1], o);
    }
    int w = t >> 6;
    if ((t & 63) == 0) { red[0][w] = p[0]; red[1][w] = p[1]; }
    __syncthreads();
    if (t == 0) {
        #pragma unroll
        for (int c = 0; c < 2; ++c)
            out[b * 2 + c] = red[c][0] + red[c][1] + red[c][2] + red[c][3] + b2[c];
    }
}

extern "C" void kernel_launch(void* const* d_in, const int* in_sizes, int n_in,
                              void* d_out, int out_size, void* d_ws, size_t ws_size,
                              hipStream_t stream) {
    (void)in_sizes; (void)n_in; (void)out_size; (void)ws_size;
    const int*   ids   = (const int*)d_in[0];
    const int*   mask  = (const int*)d_in[1];
    const float* wemb  = (const float*)d_in[2];
    const float* pemb  = (const float*)d_in[3];
    const float* emb_g = (const float*)d_in[4];
    const float* emb_b = (const float*)d_in[5];
    const float* Wq    = (const float*)d_in[6];
    const float* Wk    = (const float*)d_in[7];
    const float* Wv    = (const float*)d_in[8];
    const float* Wo    = (const float*)d_in[9];
    const float* Wi    = (const float*)d_in[10];
    const float* Wo2   = (const float*)d_in[11];
    const float* bq    = (const float*)d_in[12];
    const float* bk    = (const float*)d_in[13];
    const float* bv    = (const float*)d_in[14];
    const float* bo    = (const float*)d_in[15];
    const float* bi    = (const float*)d_in[16];
    const float* bo2   = (const float*)d_in[17];
    const float* g1    = (const float*)d_in[18];
    const float* b1    = (const float*)d_in[19];
    const float* g2    = (const float*)d_in[20];
    const float* b2    = (const float*)d_in[21];
    const float* rW1   = (const float*)d_in[22];
    const float* rb1   = (const float*)d_in[23];
    const float* rW2   = (const float*)d_in[24];
    const float* rb2   = (const float*)d_in[25];
    const float* temp  = (const float*)d_in[26];
    const float* qA    = (const float*)d_in[27];
    const float* qB    = (const float*)d_in[28];
    const float* vA    = (const float*)d_in[29];
    const float* vB    = (const float*)d_in[30];
    const float* cW1   = (const float*)d_in[31];
    const float* cb1   = (const float*)d_in[32];
    const float* cW2   = (const float*)d_in[33];
    const float* cb2   = (const float*)d_in[34];
    float* out = (float*)d_out;

    float* ws = (float*)d_ws;
    const size_t MD = (size_t)MTOK * DIM;    // 1,572,864 floats
    float* h    = ws;
    float* h2   = ws + MD;
    float* q    = ws + 2 * MD;
    float* k    = ws + 3 * MD;
    float* v    = ws + 4 * MD;
    float* o    = ws + 5 * MD;
    float* ffb  = ws + 6 * MD;               // M*FF = 4*MD floats; aliases scores
    float* h0   = ws + 10 * MD;
    int*   task = (int*)(ws + 11 * MD);
    float* scores = ffb;                     // B*H*S*S = 4*MD floats, same size

    dim3 blk(256);
    embed_ln_kernel<<<MTOK, blk, 0, stream>>>(ids, wemb, pemb, emb_g, emb_b, h0);

    for (int pass = 0; pass < 2; ++pass) {
        hipMemcpyAsync(h, h0, MD * sizeof(float), hipMemcpyDeviceToDevice, stream);
        for (int l = 0; l < LAYERS; ++l) {
            const float* Wq_l  = Wq  + (size_t)l * DIM * DIM;
            const float* Wk_l  = Wk  + (size_t)l * DIM * DIM;
            const float* Wv_l  = Wv  + (size_t)l * DIM * DIM;
            const float* Wo_l  = Wo  + (size_t)l * DIM * DIM;
            const float* Wi_l  = Wi  + (size_t)l * DIM * FFDIM;
            const float* Wo2_l = Wo2 + (size_t)l * FFDIM * DIM;
            const float* bq_l  = bq  + (size_t)l * DIM;
            const float* bk_l  = bk  + (size_t)l * DIM;
            const float* bv_l  = bv  + (size_t)l * DIM;
            const float* bo_l  = bo  + (size_t)l * DIM;
            const float* bi_l  = bi  + (size_t)l * FFDIM;
            const float* bo2_l = bo2 + (size_t)l * DIM;
            const float* g1_l  = g1  + (size_t)l * DIM;
            const float* b1_l  = b1  + (size_t)l * DIM;
            const float* g2_l  = g2  + (size_t)l * DIM;
            const float* b2_l  = b2  + (size_t)l * DIM;

            gemm_bias_kernel<0><<<dim3(DIM / 64, MTOK / 64), blk, 0, stream>>>(h, Wq_l, bq_l, q, MTOK, DIM, DIM);
            gemm_bias_kernel<0><<<dim3(DIM / 64, MTOK / 64), blk, 0, stream>>>(h, Wk_l, bk_l, k, MTOK, DIM, DIM);
            gemm_bias_kernel<0><<<dim3(DIM / 64, MTOK / 64), blk, 0, stream>>>(h, Wv_l, bv_l, v, MTOK, DIM, DIM);
            if (pass == 1) {
                lora_add_kernel<<<MTOK / 64, blk, 0, stream>>>(h, qA, qB, task, l, q);
                lora_add_kernel<<<MTOK / 64, blk, 0, stream>>>(h, vA, vB, task, l, v);
            }
            attn_scores_kernel<<<dim3(4, 4, BATCH * NH), blk, 0, stream>>>(q, k, scores);
            softmax_kernel<<<BATCH * NH * SEQ / 4, blk, 0, stream>>>(scores, mask);
            attn_pv_kernel<<<dim3(4, BATCH * NH), blk, 0, stream>>>(scores, v, o);
            gemm_bias_kernel<0><<<dim3(DIM / 64, MTOK / 64), blk, 0, stream>>>(o, Wo_l, bo_l, h2, MTOK, DIM, DIM);
            add_ln_kernel<<<MTOK, blk, 0, stream>>>(h, h2, g1_l, b1_l);
            gemm_bias_kernel<1><<<dim3(FFDIM / 64, MTOK / 64), blk, 0, stream>>>(h, Wi_l, bi_l, ffb, MTOK, FFDIM, DIM);
            gemm_bias_kernel<0><<<dim3(DIM / 64, MTOK / 64), blk, 0, stream>>>(ffb, Wo2_l, bo2_l, h2, MTOK, DIM, FFDIM);
            add_ln_kernel<<<MTOK, blk, 0, stream>>>(h, h2, g2_l, b2_l);
        }
        if (pass == 0) {
            router_kernel<<<BATCH, blk, 0, stream>>>(h, rW1, rb1, rW2, rb2, temp, out, task);
        } else {
            cls_kernel<<<BATCH, blk, 0, stream>>>(h, cW1, cb1, cW2, cb2, task, out + BATCH * TASKS);
        }
    }
}

// Round 2
// 5799.186 us; speedup vs baseline: 2.7595x; 2.7595x over previous
//
#include <hip/hip_runtime.h>
#include <math.h>

#define DIM 768
#define LAYERS 12
#define NH 12
#define HDIM 64
#define FFDIM 3072
#define SEQ 256
#define BATCH 8
#define MTOK (BATCH*SEQ)   // 2048
#define TASKS 3
#define LRANK 16
#define LORA_SC 2.0f
#define QKVLD 2304
#define ZB (BATCH*NH)      // 96

typedef unsigned short u16;
typedef __attribute__((ext_vector_type(8))) short short8;
typedef __attribute__((ext_vector_type(4))) float floatx4;
typedef __attribute__((ext_vector_type(4))) unsigned short u16x4;

__device__ __forceinline__ u16 f2bf(float f) {
    unsigned int u = __float_as_uint(f);
    u = (u + 0x7fff + ((u >> 16) & 1)) >> 16;
    return (u16)u;
}

__device__ __forceinline__ float geluf(float x) {
    float u = 0.7978845608028654f * (x + 0.044715f * x * x * x);
    u = fminf(fmaxf(u, -15.f), 15.f);
    float e = __expf(2.f * u);
    float th = (e - 1.f) / (e + 1.f);
    return 0.5f * x * (1.f + th);
}

__device__ __forceinline__ float block_sum256(float v, volatile float* sb4) {
    #pragma unroll
    for (int o = 32; o; o >>= 1) v += __shfl_down(v, o);
    int w = threadIdx.x >> 6;
    if ((threadIdx.x & 63) == 0) sb4[w] = v;
    __syncthreads();
    float total = sb4[0] + sb4[1] + sb4[2] + sb4[3];
    __syncthreads();
    return total;
}

// ============ weight transpose fp32 [K][N] -> bf16 [row_off+N][K] ============
__global__ __launch_bounds__(256) void w_transpose(
    const float* __restrict__ src, size_t src_ls,
    u16* __restrict__ dst, size_t dst_ls, int N, int dstld, int row_off) {
    __shared__ float tile[32][33];
    int l = blockIdx.z;
    int k0 = blockIdx.y * 32, n0 = blockIdx.x * 32;
    int tx = threadIdx.x & 31, ty = threadIdx.x >> 5;
    const float* s = src + (size_t)l * src_ls;
    #pragma unroll
    for (int i = 0; i < 4; ++i)
        tile[ty + i * 8][tx] = s[(size_t)(k0 + ty + i * 8) * N + n0 + tx];
    __syncthreads();
    u16* d = dst + (size_t)l * dst_ls;
    #pragma unroll
    for (int i = 0; i < 4; ++i) {
        int r = ty + i * 8;
        d[(size_t)(row_off + n0 + r) * dstld + k0 + tx] = f2bf(tile[tx][r]);
    }
}

__global__ __launch_bounds__(256) void build_bqkv(
    const float* __restrict__ bq, const float* __restrict__ bk,
    const float* __restrict__ bv, float* __restrict__ bqkv) {
    int l = blockIdx.x;
    for (int i = threadIdx.x; i < QKVLD; i += 256) {
        float v = i < DIM ? bq[l * DIM + i]
                : (i < 2 * DIM ? bk[l * DIM + i - DIM] : bv[l * DIM + i - 2 * DIM]);
        bqkv[(size_t)l * QKVLD + i] = v;
    }
}

// ============ embedding + LN (fp32 + bf16 out) ============
__global__ __launch_bounds__(256) void embed_ln_kernel(
    const int* __restrict__ ids, const float* __restrict__ wemb,
    const float* __restrict__ pemb, const float* __restrict__ g,
    const float* __restrict__ bb, float* __restrict__ out, u16* __restrict__ out_bf) {
    __shared__ float sb[4];
    int m = blockIdx.x;
    int s = m & (SEQ - 1);
    int id = ids[m];
    int t = threadIdx.x;
    float x[3];
    float sum = 0.f;
    #pragma unroll
    for (int j = 0; j < 3; ++j) {
        int d = t + j * 256;
        x[j] = wemb[(size_t)id * DIM + d] + pemb[(size_t)(s + 2) * DIM + d];
        sum += x[j];
    }
    float mean = block_sum256(sum, sb) * (1.0f / DIM);
    float vs = 0.f;
    #pragma unroll
    for (int j = 0; j < 3; ++j) { float c = x[j] - mean; vs += c * c; }
    float var = block_sum256(vs, sb) * (1.0f / DIM);
    float rstd = rsqrtf(var + 1e-5f);
    #pragma unroll
    for (int j = 0; j < 3; ++j) {
        int d = t + j * 256;
        float r = (x[j] - mean) * rstd * g[d] + bb[d];
        out[(size_t)m * DIM + d] = r;
        out_bf[(size_t)m * DIM + d] = f2bf(r);
    }
}

// ============ residual add + LN in place, + bf16 out ============
__global__ __launch_bounds__(256) void add_ln_kernel(
    float* __restrict__ h, const float* __restrict__ proj,
    const float* __restrict__ g, const float* __restrict__ bb, u16* __restrict__ h_bf) {
    __shared__ float sb[4];
    int m = blockIdx.x;
    int t = threadIdx.x;
    float x[3];
    float sum = 0.f;
    #pragma unroll
    for (int j = 0; j < 3; ++j) {
        int d = t + j * 256;
        x[j] = h[(size_t)m * DIM + d] + proj[(size_t)m * DIM + d];
        sum += x[j];
    }
    float mean = block_sum256(sum, sb) * (1.0f / DIM);
    float vs = 0.f;
    #pragma unroll
    for (int j = 0; j < 3; ++j) { float c = x[j] - mean; vs += c * c; }
    float var = block_sum256(vs, sb) * (1.0f / DIM);
    float rstd = rsqrtf(var + 1e-5f);
    #pragma unroll
    for (int j = 0; j < 3; ++j) {
        int d = t + j * 256;
        float r = (x[j] - mean) * rstd * g[d] + bb[d];
        h[(size_t)m * DIM + d] = r;
        h_bf[(size_t)m * DIM + d] = f2bf(r);
    }
}

// ============ MFMA GEMM core ============
// A: [M][K] bf16 (ld lda), B: [N][K] bf16 (ld ldb), both k-contiguous.
// BK=64 per iter: stage with global_load_lds(16B) into slot-XOR-swizzled linear LDS.
template<int ROWS>
__device__ __forceinline__ void stage_tile(const u16* srcbase, int ldk,
                                           u16* ldsbase, int wave, int lane) {
    int rin = lane >> 3, slot = lane & 7;
    #pragma unroll
    for (int c0 = 0; c0 < ROWS / 8; c0 += 4) {
        int c = c0 + wave;
        int r = c * 8 + rin;
        int scol = ((slot ^ (r & 7)) << 3);   // swizzled source col (elems)
        const u16* src = srcbase + (size_t)r * ldk + scol;
        __builtin_amdgcn_global_load_lds(
            (const __attribute__((address_space(1))) unsigned int*)src,
            (__attribute__((address_space(3))) unsigned int*)(ldsbase + (size_t)c * 512 + lane * 8),
            16, 0, 0);
    }
}

__device__ __forceinline__ short8 frag_read(const u16* ldsbase, int r, int s) {
    return *(const short8*)(ldsbase + r * 64 + (((s ^ (r & 7)) << 3)));
}

template<int BM, int BN, int ACT, int OUTMODE>   // OUTMODE: 0=f32, 1=bf16, 2=both
__device__ __forceinline__ void gemm_body(
    const u16* __restrict__ A, int lda, const u16* __restrict__ B, int ldb,
    const float* __restrict__ bias, float* __restrict__ Cf, u16* __restrict__ Cb,
    int ldc, int K, int m0, int n0, u16* lds) {
    u16* As = lds;
    u16* Bs = lds + BM * 64;
    int t = threadIdx.x, lane = t & 63, wave = t >> 6;
    int wr = wave >> 1, wc = wave & 1;
    constexpr int FM = BM / 32, FN = BN / 32;
    int wm0 = wr * (BM / 2), wn0 = wc * (BN / 2);
    floatx4 acc[FM][FN];
    #pragma unroll
    for (int i = 0; i < FM; ++i)
        #pragma unroll
        for (int j = 0; j < FN; ++j)
            acc[i][j] = (floatx4){0.f, 0.f, 0.f, 0.f};
    int lr = lane & 15, kg = lane >> 4;
    for (int k0 = 0; k0 < K; k0 += 64) {
        stage_tile<BM>(A + (size_t)m0 * lda + k0, lda, As, wave, lane);
        stage_tile<BN>(B + (size_t)n0 * ldb + k0, ldb, Bs, wave, lane);
        __syncthreads();
        #pragma unroll
        for (int kk = 0; kk < 2; ++kk) {
            short8 af[FM], bfr[FN];
            #pragma unroll
            for (int mi = 0; mi < FM; ++mi)
                af[mi] = frag_read(As, wm0 + mi * 16 + lr, kk * 4 + kg);
            #pragma unroll
            for (int ni = 0; ni < FN; ++ni)
                bfr[ni] = frag_read(Bs, wn0 + ni * 16 + lr, kk * 4 + kg);
            #pragma unroll
            for (int mi = 0; mi < FM; ++mi)
                #pragma unroll
                for (int ni = 0; ni < FN; ++ni)
                    acc[mi][ni] = __builtin_amdgcn_mfma_f32_16x16x32_bf16(
                        af[mi], bfr[ni], acc[mi][ni], 0, 0, 0);
        }
        __syncthreads();
    }
    int cr = (lane >> 4) * 4, cc = lane & 15;
    #pragma unroll
    for (int mi = 0; mi < FM; ++mi) {
        #pragma unroll
        for (int ni = 0; ni < FN; ++ni) {
            int col = n0 + wn0 + ni * 16 + cc;
            float bsv = bias ? bias[col] : 0.f;
            #pragma unroll
            for (int j = 0; j < 4; ++j) {
                int row = m0 + wm0 + mi * 16 + cr + j;
                float r = acc[mi][ni][j] + bsv;
                if (ACT == 1) r = geluf(r);
                if (OUTMODE == 0 || OUTMODE == 2) Cf[(size_t)row * ldc + col] = r;
                if (OUTMODE == 1 || OUTMODE == 2) Cb[(size_t)row * ldc + col] = f2bf(r);
            }
        }
    }
}

template<int BM, int BN, int ACT, int OUTMODE>
__global__ __launch_bounds__(256) void gemm_mfma(
    const u16* __restrict__ A, int lda, const u16* __restrict__ B, int ldb,
    const float* __restrict__ bias, float* __restrict__ Cf, u16* __restrict__ Cb,
    int ldc, int K) {
    __shared__ u16 lds[(BM + BN) * 64];
    gemm_body<BM, BN, ACT, OUTMODE>(A, lda, B, ldb, bias, Cf, Cb, ldc, K,
                                    blockIdx.y * BM, blockIdx.x * BN, lds);
}

// ============ batched attention QK^T: scores[z][q][k] = Q·K^T (raw) ============
__global__ __launch_bounds__(256) void attn_qk(
    const u16* __restrict__ qkv_bf, float* __restrict__ scores) {
    __shared__ u16 lds[(128 + 128) * 64];
    int z = blockIdx.z, b = z / NH, h = z % NH;
    const u16* A = qkv_bf + (size_t)b * SEQ * QKVLD + h * HDIM;
    const u16* B = A + DIM;
    float* C = scores + (size_t)z * SEQ * SEQ;
    gemm_body<128, 128, 0, 0>(A, QKVLD, B, QKVLD, nullptr, C, nullptr, SEQ, HDIM,
                              blockIdx.y * 128, blockIdx.x * 128, lds);
}

// ============ V transpose: vT[z][d][k] = V[z-batch rows][d] ============
__global__ __launch_bounds__(256) void v_transpose(
    const u16* __restrict__ qkv_bf, u16* __restrict__ vT) {
    __shared__ u16 tile[64][65];
    int kt = blockIdx.x, z = blockIdx.y;
    int b = z / NH, h = z % NH;
    int t = threadIdx.x;
    const u16* src = qkv_bf + (size_t)(b * SEQ + kt * 64) * QKVLD + 2 * DIM + h * HDIM;
    for (int i = t; i < 1024; i += 256) {
        int r = i >> 4, c4 = (i & 15) << 2;
        u16x4 v = *(const u16x4*)(src + (size_t)r * QKVLD + c4);
        tile[r][c4 + 0] = v[0]; tile[r][c4 + 1] = v[1];
        tile[r][c4 + 2] = v[2]; tile[r][c4 + 3] = v[3];
    }
    __syncthreads();
    u16* dst = vT + (size_t)z * HDIM * SEQ;
    for (int i = t; i < 1024; i += 256) {
        int d = i >> 4, k4 = (i & 15) << 2;
        u16x4 w;
        w[0] = tile[k4 + 0][d]; w[1] = tile[k4 + 1][d];
        w[2] = tile[k4 + 2][d]; w[3] = tile[k4 + 3][d];
        *(u16x4*)(dst + (size_t)d * SEQ + kt * 64 + k4) = w;
    }
}

// ============ softmax: fp32 scores -> bf16 P ============
__global__ __launch_bounds__(256) void softmax_kernel(
    const float* __restrict__ scores, const int* __restrict__ mask,
    u16* __restrict__ p_bf) {
    int wave = threadIdx.x >> 6, lane = threadIdx.x & 63;
    int g = blockIdx.x * 4 + wave;      // row over ZB*SEQ
    int b = g / (NH * SEQ);
    const float* row = scores + (size_t)g * SEQ;
    float4 sv = *(const float4*)(row + lane * 4);
    int4 mv = *(const int4*)(mask + b * SEQ + lane * 4);
    float s[4] = {sv.x, sv.y, sv.z, sv.w};
    int mm[4] = {mv.x, mv.y, mv.z, mv.w};
    float m = -1e30f;
    #pragma unroll
    for (int j = 0; j < 4; ++j) {
        s[j] = s[j] * 0.125f + (1.0f - (float)mm[j]) * -1e9f;
        m = fmaxf(m, s[j]);
    }
    #pragma unroll
    for (int o = 32; o; o >>= 1) m = fmaxf(m, __shfl_xor(m, o));
    float sum = 0.f;
    #pragma unroll
    for (int j = 0; j < 4; ++j) { s[j] = __expf(s[j] - m); sum += s[j]; }
    #pragma unroll
    for (int o = 32; o; o >>= 1) sum += __shfl_xor(sum, o);
    float inv = 1.0f / sum;
    u16x4 o4;
    #pragma unroll
    for (int j = 0; j < 4; ++j) o4[j] = f2bf(s[j] * inv);
    *(u16x4*)(p_bf + (size_t)g * SEQ + lane * 4) = o4;
}

// ============ batched PV: o_bf[q][h*64+d] = P·V ============
__global__ __launch_bounds__(256) void attn_pv(
    const u16* __restrict__ p_bf, const u16* __restrict__ vT, u16* __restrict__ o_bf) {
    __shared__ u16 lds[(64 + 64) * 64];
    int z = blockIdx.z, b = z / NH, h = z % NH;
    const u16* A = p_bf + (size_t)z * SEQ * SEQ;
    const u16* B = vT + (size_t)z * HDIM * SEQ;
    u16* C = o_bf + (size_t)b * SEQ * DIM + h * HDIM;
    gemm_body<64, 64, 0, 1>(A, SEQ, B, SEQ, nullptr, nullptr, C, DIM, SEQ,
                            blockIdx.y * 64, 0, lds);
}

// ============ fp32 -> bf16 bulk convert ============
__global__ __launch_bounds__(256) void f32_to_bf16_kernel(
    const float* __restrict__ src, u16* __restrict__ dst, int n4) {
    int i = blockIdx.x * 256 + threadIdx.x;
    if (i < n4) {
        float4 v = *(const float4*)(src + (size_t)i * 4);
        u16x4 o = {f2bf(v.x), f2bf(v.y), f2bf(v.z), f2bf(v.w)};
        *(u16x4*)(dst + (size_t)i * 4) = o;
    }
}

// ============ LoRA: q += 2 * (h @ A^T) @ B^T (fp32, strided q) ============
__global__ __launch_bounds__(256) void lora_add_kernel(
    const float* __restrict__ h, const float* __restrict__ Abase,
    const float* __restrict__ Bbase, const int* __restrict__ task,
    int layer, float* __restrict__ q, int qld) {
    int m0 = blockIdx.x * 64;
    int b = m0 >> 8;
    int tk = task[b];
    const float* Ap = Abase + (size_t)(tk * LAYERS + layer) * LRANK * DIM;
    const float* Bp = Bbase + (size_t)(tk * LAYERS + layer) * DIM * LRANK;
    __shared__ float tmp[64][16];
    int t = threadIdx.x;
    int row = t & 63, rb = t >> 6;
    float s[4] = {0.f, 0.f, 0.f, 0.f};
    const float* hrow = h + (size_t)(m0 + row) * DIM;
    for (int d = 0; d < DIM; d += 4) {
        float4 hv = *(const float4*)&hrow[d];
        #pragma unroll
        for (int i = 0; i < 4; ++i) {
            float4 av = *(const float4*)&Ap[(size_t)(rb + i * 4) * DIM + d];
            s[i] += hv.x * av.x + hv.y * av.y + hv.z * av.z + hv.w * av.w;
        }
    }
    #pragma unroll
    for (int i = 0; i < 4; ++i) tmp[row][rb + i * 4] = s[i];
    __syncthreads();
    float qbr[3][16];
    #pragma unroll
    for (int c = 0; c < 3; ++c)
        #pragma unroll
        for (int r4 = 0; r4 < 4; ++r4)
            *(float4*)&qbr[c][r4 * 4] = *(const float4*)&Bp[(size_t)(t * 3 + c) * LRANK + r4 * 4];
    for (int rr = 0; rr < 64; ++rr) {
        float a0 = 0.f, a1 = 0.f, a2 = 0.f;
        #pragma unroll
        for (int r = 0; r < 16; ++r) {
            float tv = tmp[rr][r];
            a0 += tv * qbr[0][r];
            a1 += tv * qbr[1][r];
            a2 += tv * qbr[2][r];
        }
        float* qrow = q + (size_t)(m0 + rr) * qld + t * 3;
        qrow[0] += LORA_SC * a0;
        qrow[1] += LORA_SC * a1;
        qrow[2] += LORA_SC * a2;
    }
}

// ============ router head ============
__global__ __launch_bounds__(256) void router_kernel(
    const float* __restrict__ hb, const float* __restrict__ W1,
    const float* __restrict__ b1, const float* __restrict__ W2,
    const float* __restrict__ b2, const float* __restrict__ temp,
    float* __restrict__ out_logits, int* __restrict__ task) {
    int b = blockIdx.x;
    int t = threadIdx.x;
    __shared__ float cls[DIM];
    __shared__ float y1[DIM];
    __shared__ float red[3][4];
    #pragma unroll
    for (int j = 0; j < 3; ++j) cls[t + j * 256] = hb[(size_t)(b * SEQ) * DIM + t + j * 256];
    __syncthreads();
    #pragma unroll
    for (int j = 0; j < 3; ++j) {
        int col = t + j * 256;
        float s = b1[col];
        for (int d = 0; d < DIM; ++d) s += cls[d] * W1[(size_t)d * DIM + col];
        y1[col] = fmaxf(s, 0.0f);
    }
    __syncthreads();
    float p[3] = {0.f, 0.f, 0.f};
    #pragma unroll
    for (int j = 0; j < 3; ++j) {
        int col = t + j * 256;
        float y = y1[col];
        p[0] += y * W2[col * 3 + 0];
        p[1] += y * W2[col * 3 + 1];
        p[2] += y * W2[col * 3 + 2];
    }
    #pragma unroll
    for (int o = 32; o; o >>= 1) {
        p[0] += __shfl_down(p[0], o);
        p[1] += __shfl_down(p[1], o);
        p[2] += __shfl_down(p[2], o);
    }
    int w = t >> 6;
    if ((t & 63) == 0) { red[0][w] = p[0]; red[1][w] = p[1]; red[2][w] = p[2]; }
    __syncthreads();
    if (t == 0) {
        float tt = fmaxf(temp[0], 0.05f);
        float l[3];
        #pragma unroll
        for (int c = 0; c < 3; ++c) {
            l[c] = (red[c][0] + red[c][1] + red[c][2] + red[c][3] + b2[c]) / tt;
            out_logits[b * 3 + c] = l[c];
        }
        int bt = 0; float bv = l[0];
        if (l[1] > bv) { bv = l[1]; bt = 1; }
        if (l[2] > bv) { bv = l[2]; bt = 2; }
        task[b] = bt;
    }
}

// ============ final classifier head ============
__global__ __launch_bounds__(256) void cls_kernel(
    const float* __restrict__ ha, const float* __restrict__ cW1,
    const float* __restrict__ cb1, const float* __restrict__ cW2,
    const float* __restrict__ cb2, const int* __restrict__ task,
    float* __restrict__ out) {
    int b = blockIdx.x;
    int t = threadIdx.x;
    int tk = task[b];
    const float* W1 = cW1 + (size_t)tk * DIM * DIM;
    const float* b1 = cb1 + tk * DIM;
    const float* W2 = cW2 + (size_t)tk * DIM * 2;
    const float* b2 = cb2 + tk * 2;
    __shared__ float f[DIM];
    __shared__ float y1[DIM];
    __shared__ float red[2][4];
    #pragma unroll
    for (int j = 0; j < 3; ++j) f[t + j * 256] = ha[(size_t)(b * SEQ) * DIM + t + j * 256];
    __syncthreads();
    #pragma unroll
    for (int j = 0; j < 3; ++j) {
        int col = t + j * 256;
        float s = b1[col];
        for (int d = 0; d < DIM; ++d) s += f[d] * W1[(size_t)d * DIM + col];
        y1[col] = tanhf(s);
    }
    __syncthreads();
    float p[2] = {0.f, 0.f};
    #pragma unroll
    for (int j = 0; j < 3; ++j) {
        int col = t + j * 256;
        float y = y1[col];
        p[0] += y * W2[col * 2 + 0];
        p[1] += y * W2[col * 2 + 1];
    }
    #pragma unroll
    for (int o = 32; o; o >>= 1) {
        p[0] += __shfl_down(p[0], o);
        p[1] += __shfl_down(p[1], o);
    }
    int w = t >> 6;
    if ((t & 63) == 0) { red[0][w] = p[0]; red[1][w] = p[1]; }
    __syncthreads();
    if (t == 0) {
        #pragma unroll
        for (int c = 0; c < 2; ++c)
            out[b * 2 + c] = red[c][0] + red[c][1] + red[c][2] + red[c][3] + b2[c];
    }
}

extern "C" void kernel_launch(void* const* d_in, const int* in_sizes, int n_in,
                              void* d_out, int out_size, void* d_ws, size_t ws_size,
                              hipStream_t stream) {
    (void)in_sizes; (void)n_in; (void)out_size; (void)ws_size;
    const int*   ids   = (const int*)d_in[0];
    const int*   mask  = (const int*)d_in[1];
    const float* wemb  = (const float*)d_in[2];
    const float* pemb  = (const float*)d_in[3];
    const float* emb_g = (const float*)d_in[4];
    const float* emb_b = (const float*)d_in[5];
    const float* Wq    = (const float*)d_in[6];
    const float* Wk    = (const float*)d_in[7];
    const float* Wv    = (const float*)d_in[8];
    const float* Wo    = (const float*)d_in[9];
    const float* Wi    = (const float*)d_in[10];
    const float* Wo2   = (const float*)d_in[11];
    const float* bq    = (const float*)d_in[12];
    const float* bk    = (const float*)d_in[13];
    const float* bv    = (const float*)d_in[14];
    const float* bo    = (const float*)d_in[15];
    const float* bi    = (const float*)d_in[16];
    const float* bo2   = (const float*)d_in[17];
    const float* g1    = (const float*)d_in[18];
    const float* b1    = (const float*)d_in[19];
    const float* g2    = (const float*)d_in[20];
    const float* b2    = (const float*)d_in[21];
    const float* rW1   = (const float*)d_in[22];
    const float* rb1   = (const float*)d_in[23];
    const float* rW2   = (const float*)d_in[24];
    const float* rb2   = (const float*)d_in[25];
    const float* temp  = (const float*)d_in[26];
    const float* qA    = (const float*)d_in[27];
    const float* qB    = (const float*)d_in[28];
    const float* vA    = (const float*)d_in[29];
    const float* vB    = (const float*)d_in[30];
    const float* cW1   = (const float*)d_in[31];
    const float* cb1   = (const float*)d_in[32];
    const float* cW2   = (const float*)d_in[33];
    const float* cb2   = (const float*)d_in[34];
    float* out = (float*)d_out;

    const size_t MD = (size_t)MTOK * DIM;
    char* p = (char*)d_ws;
    auto alloc = [&](size_t bytes) { char* r = p; p += (bytes + 255) & ~(size_t)255; return r; };
    float* h      = (float*)alloc(MD * 4);
    float* h2     = (float*)alloc(MD * 4);
    float* qkv    = (float*)alloc((size_t)MTOK * QKVLD * 4);
    float* h0     = (float*)alloc(MD * 4);
    float* scores = (float*)alloc((size_t)ZB * SEQ * SEQ * 4);
    u16* h_bf   = (u16*)alloc(MD * 2);
    u16* h0_bf  = (u16*)alloc(MD * 2);
    u16* o_bf   = (u16*)alloc(MD * 2);
    u16* qkv_bf = (u16*)alloc((size_t)MTOK * QKVLD * 2);
    u16* p_bf   = (u16*)alloc((size_t)ZB * SEQ * SEQ * 2);
    u16* ffb_bf = p_bf;   // alias: disjoint lifetimes (attention vs FF within a layer)
    u16* vT     = (u16*)alloc((size_t)ZB * HDIM * SEQ * 2);
    float* bqkv = (float*)alloc((size_t)LAYERS * QKVLD * 4);
    int* task   = (int*)alloc(256);
    u16* WqkvT  = (u16*)alloc((size_t)LAYERS * QKVLD * DIM * 2);
    u16* WoT    = (u16*)alloc((size_t)LAYERS * DIM * DIM * 2);
    u16* WiT    = (u16*)alloc((size_t)LAYERS * FFDIM * DIM * 2);
    u16* Wo2T   = (u16*)alloc((size_t)LAYERS * DIM * FFDIM * 2);

    dim3 blk(256);
    // --- weight prep (bf16, [N][K]) ---
    w_transpose<<<dim3(24, 24, LAYERS), blk, 0, stream>>>(Wq, (size_t)DIM * DIM, WqkvT, (size_t)QKVLD * DIM, DIM, DIM, 0);
    w_transpose<<<dim3(24, 24, LAYERS), blk, 0, stream>>>(Wk, (size_t)DIM * DIM, WqkvT, (size_t)QKVLD * DIM, DIM, DIM, DIM);
    w_transpose<<<dim3(24, 24, LAYERS), blk, 0, stream>>>(Wv, (size_t)DIM * DIM, WqkvT, (size_t)QKVLD * DIM, DIM, DIM, 2 * DIM);
    w_transpose<<<dim3(24, 24, LAYERS), blk, 0, stream>>>(Wo, (size_t)DIM * DIM, WoT, (size_t)DIM * DIM, DIM, DIM, 0);
    w_transpose<<<dim3(96, 24, LAYERS), blk, 0, stream>>>(Wi, (size_t)DIM * FFDIM, WiT, (size_t)FFDIM * DIM, FFDIM, DIM, 0);
    w_transpose<<<dim3(24, 96, LAYERS), blk, 0, stream>>>(Wo2, (size_t)FFDIM * DIM, Wo2T, (size_t)DIM * FFDIM, DIM, FFDIM, 0);
    build_bqkv<<<LAYERS, blk, 0, stream>>>(bq, bk, bv, bqkv);

    embed_ln_kernel<<<MTOK, blk, 0, stream>>>(ids, wemb, pemb, emb_g, emb_b, h0, h0_bf);

    for (int pass = 0; pass < 2; ++pass) {
        hipMemcpyAsync(h, h0, MD * 4, hipMemcpyDeviceToDevice, stream);
        hipMemcpyAsync(h_bf, h0_bf, MD * 2, hipMemcpyDeviceToDevice, stream);
        for (int l = 0; l < LAYERS; ++l) {
            const u16* WqkvT_l = WqkvT + (size_t)l * QKVLD * DIM;
            const u16* WoT_l   = WoT   + (size_t)l * DIM * DIM;
            const u16* WiT_l   = WiT   + (size_t)l * FFDIM * DIM;
            const u16* Wo2T_l  = Wo2T  + (size_t)l * DIM * FFDIM;
            const float* bqkv_l = bqkv + (size_t)l * QKVLD;
            const float* bo_l  = bo  + (size_t)l * DIM;
            const float* bi_l  = bi  + (size_t)l * FFDIM;
            const float* bo2_l = bo2 + (size_t)l * DIM;
            const float* g1_l  = g1  + (size_t)l * DIM;
            const float* b1_l  = b1  + (size_t)l * DIM;
            const float* g2_l  = g2  + (size_t)l * DIM;
            const float* b2_l  = b2  + (size_t)l * DIM;

            if (pass == 0) {
                gemm_mfma<128, 128, 0, 2><<<dim3(QKVLD / 128, MTOK / 128), blk, 0, stream>>>(
                    h_bf, DIM, WqkvT_l, DIM, bqkv_l, qkv, qkv_bf, QKVLD, DIM);
            } else {
                gemm_mfma<128, 128, 0, 0><<<dim3(QKVLD / 128, MTOK / 128), blk, 0, stream>>>(
                    h_bf, DIM, WqkvT_l, DIM, bqkv_l, qkv, nullptr, QKVLD, DIM);
                lora_add_kernel<<<MTOK / 64, blk, 0, stream>>>(h, qA, qB, task, l, qkv, QKVLD);
                lora_add_kernel<<<MTOK / 64, blk, 0, stream>>>(h, vA, vB, task, l, qkv + 2 * DIM, QKVLD);
                f32_to_bf16_kernel<<<(MTOK * QKVLD / 4 + 255) / 256, blk, 0, stream>>>(
                    qkv, qkv_bf, MTOK * QKVLD / 4);
            }
            v_transpose<<<dim3(SEQ / 64, ZB), blk, 0, stream>>>(qkv_bf, vT);
            attn_qk<<<dim3(2, 2, ZB), blk, 0, stream>>>(qkv_bf, scores);
            softmax_kernel<<<ZB * SEQ / 4, blk, 0, stream>>>(scores, mask, p_bf);
            attn_pv<<<dim3(1, 4, ZB), blk, 0, stream>>>(p_bf, vT, o_bf);
            gemm_mfma<64, 128, 0, 0><<<dim3(DIM / 128, MTOK / 64), blk, 0, stream>>>(
                o_bf, DIM, WoT_l, DIM, bo_l, h2, nullptr, DIM, DIM);
            add_ln_kernel<<<MTOK, blk, 0, stream>>>(h, h2, g1_l, b1_l, h_bf);
            gemm_mfma<128, 128, 1, 1><<<dim3(FFDIM / 128, MTOK / 128), blk, 0, stream>>>(
                h_bf, DIM, WiT_l, DIM, bi_l, nullptr, ffb_bf, FFDIM, DIM);
            gemm_mfma<64, 128, 0, 0><<<dim3(DIM / 128, MTOK / 64), blk, 0, stream>>>(
                ffb_bf, FFDIM, Wo2T_l, FFDIM, bo2_l, h2, nullptr, DIM, FFDIM);
            add_ln_kernel<<<MTOK, blk, 0, stream>>>(h, h2, g2_l, b2_l, h_bf);
        }
        if (pass == 0) {
            router_kernel<<<BATCH, blk, 0, stream>>>(h, rW1, rb1, rW2, rb2, temp, out, task);
        } else {
            cls_kernel<<<BATCH, blk, 0, stream>>>(h, cW1, cb1, cW2, cb2, task, out + BATCH * TASKS);
        }
    }
}

// Round 3
// 4648.070 us; speedup vs baseline: 3.4430x; 1.2477x over previous
//
#include <hip/hip_runtime.h>
#include <math.h>

#define DIM 768
#define LAYERS 12
#define NH 12
#define HDIM 64
#define FFDIM 3072
#define SEQ 256
#define BATCH 8
#define MTOK (BATCH*SEQ)   // 2048
#define TASKS 3
#define LRANK 16
#define LORA_SC 2.0f
#define QKVLD 2304
#define ZB (BATCH*NH)      // 96

typedef unsigned short u16;
typedef __attribute__((ext_vector_type(8))) short short8;
typedef __attribute__((ext_vector_type(4))) float floatx4;
typedef __attribute__((ext_vector_type(4))) unsigned short u16x4;

__device__ __forceinline__ u16 f2bf(float f) {
    unsigned int u = __float_as_uint(f);
    u = (u + 0x7fff + ((u >> 16) & 1)) >> 16;
    return (u16)u;
}

__device__ __forceinline__ float geluf(float x) {
    float u = 0.7978845608028654f * (x + 0.044715f * x * x * x);
    u = fminf(fmaxf(u, -15.f), 15.f);
    float e = __expf(2.f * u);
    float th = (e - 1.f) / (e + 1.f);
    return 0.5f * x * (1.f + th);
}

__device__ __forceinline__ float block_sum256(float v, volatile float* sb4) {
    #pragma unroll
    for (int o = 32; o; o >>= 1) v += __shfl_down(v, o);
    int w = threadIdx.x >> 6;
    if ((threadIdx.x & 63) == 0) sb4[w] = v;
    __syncthreads();
    float total = sb4[0] + sb4[1] + sb4[2] + sb4[3];
    __syncthreads();
    return total;
}

// ============ weight transpose fp32 [K][N] -> bf16 [row_off+N][K] ============
__global__ __launch_bounds__(256) void w_transpose(
    const float* __restrict__ src, size_t src_ls,
    u16* __restrict__ dst, size_t dst_ls, int N, int dstld, int row_off) {
    __shared__ float tile[32][33];
    int l = blockIdx.z;
    int k0 = blockIdx.y * 32, n0 = blockIdx.x * 32;
    int tx = threadIdx.x & 31, ty = threadIdx.x >> 5;
    const float* s = src + (size_t)l * src_ls;
    #pragma unroll
    for (int i = 0; i < 4; ++i)
        tile[ty + i * 8][tx] = s[(size_t)(k0 + ty + i * 8) * N + n0 + tx];
    __syncthreads();
    u16* d = dst + (size_t)l * dst_ls;
    #pragma unroll
    for (int i = 0; i < 4; ++i) {
        int r = ty + i * 8;
        d[(size_t)(row_off + n0 + r) * dstld + k0 + tx] = f2bf(tile[tx][r]);
    }
}

__global__ __launch_bounds__(256) void build_bqkv(
    const float* __restrict__ bq, const float* __restrict__ bk,
    const float* __restrict__ bv, float* __restrict__ bqkv) {
    int l = blockIdx.x;
    for (int i = threadIdx.x; i < QKVLD; i += 256) {
        float v = i < DIM ? bq[l * DIM + i]
                : (i < 2 * DIM ? bk[l * DIM + i - DIM] : bv[l * DIM + i - 2 * DIM]);
        bqkv[(size_t)l * QKVLD + i] = v;
    }
}

// ============ embedding + LN (fp32 + bf16 out) ============
__global__ __launch_bounds__(256) void embed_ln_kernel(
    const int* __restrict__ ids, const float* __restrict__ wemb,
    const float* __restrict__ pemb, const float* __restrict__ g,
    const float* __restrict__ bb, float* __restrict__ out, u16* __restrict__ out_bf) {
    __shared__ float sb[4];
    int m = blockIdx.x;
    int s = m & (SEQ - 1);
    int id = ids[m];
    int t = threadIdx.x;
    float x[3];
    float sum = 0.f;
    #pragma unroll
    for (int j = 0; j < 3; ++j) {
        int d = t + j * 256;
        x[j] = wemb[(size_t)id * DIM + d] + pemb[(size_t)(s + 2) * DIM + d];
        sum += x[j];
    }
    float mean = block_sum256(sum, sb) * (1.0f / DIM);
    float vs = 0.f;
    #pragma unroll
    for (int j = 0; j < 3; ++j) { float c = x[j] - mean; vs += c * c; }
    float var = block_sum256(vs, sb) * (1.0f / DIM);
    float rstd = rsqrtf(var + 1e-5f);
    #pragma unroll
    for (int j = 0; j < 3; ++j) {
        int d = t + j * 256;
        float r = (x[j] - mean) * rstd * g[d] + bb[d];
        out[(size_t)m * DIM + d] = r;
        out_bf[(size_t)m * DIM + d] = f2bf(r);
    }
}

// ============ residual add + LN in place, + bf16 out ============
__global__ __launch_bounds__(256) void add_ln_kernel(
    float* __restrict__ h, const float* __restrict__ proj,
    const float* __restrict__ g, const float* __restrict__ bb, u16* __restrict__ h_bf) {
    __shared__ float sb[4];
    int m = blockIdx.x;
    int t = threadIdx.x;
    float x[3];
    float sum = 0.f;
    #pragma unroll
    for (int j = 0; j < 3; ++j) {
        int d = t + j * 256;
        x[j] = h[(size_t)m * DIM + d] + proj[(size_t)m * DIM + d];
        sum += x[j];
    }
    float mean = block_sum256(sum, sb) * (1.0f / DIM);
    float vs = 0.f;
    #pragma unroll
    for (int j = 0; j < 3; ++j) { float c = x[j] - mean; vs += c * c; }
    float var = block_sum256(vs, sb) * (1.0f / DIM);
    float rstd = rsqrtf(var + 1e-5f);
    #pragma unroll
    for (int j = 0; j < 3; ++j) {
        int d = t + j * 256;
        float r = (x[j] - mean) * rstd * g[d] + bb[d];
        h[(size_t)m * DIM + d] = r;
        h_bf[(size_t)m * DIM + d] = f2bf(r);
    }
}

// ============ MFMA GEMM core ============
// A: [M][K] bf16 (ld lda), B: [N][K] bf16 (ld ldb), both k-contiguous.
// BK=64 per iter: stage with global_load_lds(16B) into slot-XOR-swizzled linear LDS.
template<int ROWS>
__device__ __forceinline__ void stage_tile(const u16* srcbase, int ldk,
                                           u16* ldsbase, int wave, int lane) {
    int rin = lane >> 3, slot = lane & 7;
    #pragma unroll
    for (int c0 = 0; c0 < ROWS / 8; c0 += 4) {
        int c = c0 + wave;
        int r = c * 8 + rin;
        int scol = ((slot ^ (r & 7)) << 3);   // pre-swizzled source col (elems)
        const u16* src = srcbase + (size_t)r * ldk + scol;
        __builtin_amdgcn_global_load_lds(
            (const __attribute__((address_space(1))) unsigned int*)src,
            (__attribute__((address_space(3))) unsigned int*)(ldsbase + (size_t)c * 512 + lane * 8),
            16, 0, 0);
    }
}

__device__ __forceinline__ short8 frag_read(const u16* ldsbase, int r, int s) {
    return *(const short8*)(ldsbase + r * 64 + (((s ^ (r & 7)) << 3)));
}

template<int BM, int BN>
__device__ __forceinline__ void gemm_core(
    const u16* __restrict__ A, int lda, const u16* __restrict__ B, int ldb,
    int K, int m0, int n0, u16* lds, floatx4 (&acc)[BM / 32][BN / 32]) {
    u16* As = lds;
    u16* Bs = lds + BM * 64;
    int t = threadIdx.x, lane = t & 63, wave = t >> 6;
    int wr = wave >> 1, wc = wave & 1;
    constexpr int FM = BM / 32, FN = BN / 32;
    int wm0 = wr * (BM / 2), wn0 = wc * (BN / 2);
    #pragma unroll
    for (int i = 0; i < FM; ++i)
        #pragma unroll
        for (int j = 0; j < FN; ++j)
            acc[i][j] = (floatx4){0.f, 0.f, 0.f, 0.f};
    int lr = lane & 15, kg = lane >> 4;
    for (int k0 = 0; k0 < K; k0 += 64) {
        stage_tile<BM>(A + (size_t)m0 * lda + k0, lda, As, wave, lane);
        stage_tile<BN>(B + (size_t)n0 * ldb + k0, ldb, Bs, wave, lane);
        __syncthreads();
        #pragma unroll
        for (int kk = 0; kk < 2; ++kk) {
            short8 af[FM], bfr[FN];
            #pragma unroll
            for (int mi = 0; mi < FM; ++mi)
                af[mi] = frag_read(As, wm0 + mi * 16 + lr, kk * 4 + kg);
            #pragma unroll
            for (int ni = 0; ni < FN; ++ni)
                bfr[ni] = frag_read(Bs, wn0 + ni * 16 + lr, kk * 4 + kg);
            #pragma unroll
            for (int mi = 0; mi < FM; ++mi)
                #pragma unroll
                for (int ni = 0; ni < FN; ++ni)
                    acc[mi][ni] = __builtin_amdgcn_mfma_f32_16x16x32_bf16(
                        af[mi], bfr[ni], acc[mi][ni], 0, 0, 0);
        }
        __syncthreads();
    }
}

// ---- standard GEMM kernel: bias + optional GELU, f32 and/or bf16 out ----
template<int BM, int BN, int ACT, int OUTMODE>   // OUTMODE: 0=f32, 1=bf16
__global__ __launch_bounds__(256) void gemm_mfma(
    const u16* __restrict__ A, int lda, const u16* __restrict__ B, int ldb,
    const float* __restrict__ bias, float* __restrict__ Cf, u16* __restrict__ Cb,
    int ldc, int K) {
    __shared__ u16 lds[(BM + BN) * 64];
    constexpr int FM = BM / 32, FN = BN / 32;
    floatx4 acc[FM][FN];
    int m0 = blockIdx.y * BM, n0 = blockIdx.x * BN;
    gemm_core<BM, BN>(A, lda, B, ldb, K, m0, n0, lds, acc);
    int t = threadIdx.x, lane = t & 63, wave = t >> 6;
    int wr = wave >> 1, wc = wave & 1;
    int wm0 = wr * (BM / 2), wn0 = wc * (BN / 2);
    int cr = (lane >> 4) * 4, cc = lane & 15;
    #pragma unroll
    for (int mi = 0; mi < FM; ++mi) {
        #pragma unroll
        for (int ni = 0; ni < FN; ++ni) {
            int col = n0 + wn0 + ni * 16 + cc;
            float bsv = bias ? bias[col] : 0.f;
            #pragma unroll
            for (int j = 0; j < 4; ++j) {
                int row = m0 + wm0 + mi * 16 + cr + j;
                float r = acc[mi][ni][j] + bsv;
                if (ACT == 1) r = geluf(r);
                if (OUTMODE == 0) Cf[(size_t)row * ldc + col] = r;
                else Cb[(size_t)row * ldc + col] = f2bf(r);
            }
        }
    }
}

// ---- QKV GEMM: bias, optional fused LoRA, bf16 out, fused vT scatter ----
template<int LORA>
__global__ __launch_bounds__(256) void gemm_qkv(
    const u16* __restrict__ A, const u16* __restrict__ Bw,
    const float* __restrict__ bias, u16* __restrict__ qkv_bf,
    u16* __restrict__ vT,
    const float* __restrict__ tq, const float* __restrict__ tv,
    const float* __restrict__ qBb, const float* __restrict__ vBb,
    const int* __restrict__ taskp, int layer) {
    __shared__ u16 lds[(128 + 128) * 64];
    floatx4 acc[4][4];
    int m0 = blockIdx.y * 128, n0 = blockIdx.x * 128;
    gemm_core<128, 128>(A, DIM, Bw, DIM, DIM, m0, n0, lds, acc);
    int t = threadIdx.x, lane = t & 63, wave = t >> 6;
    int wr = wave >> 1, wc = wave & 1;
    int wm0 = wr * 64, wn0 = wc * 64;
    int cr = (lane >> 4) * 4, cc = lane & 15;
    const float* tvec = nullptr;
    const float* Bmat = nullptr;
    if (LORA) {
        int tk = taskp[m0 >> 8];   // 128-row tile lies within one batch
        if (n0 < DIM) {
            tvec = tq;
            Bmat = qBb + ((size_t)tk * LAYERS + layer) * DIM * LRANK;
        } else if (n0 >= 2 * DIM) {
            tvec = tv;
            Bmat = vBb + ((size_t)tk * LAYERS + layer) * DIM * LRANK - (size_t)2 * DIM * LRANK;
        }
    }
    bool vrange = (n0 >= 2 * DIM);
    #pragma unroll
    for (int mi = 0; mi < 4; ++mi) {
        #pragma unroll
        for (int j = 0; j < 4; ++j) {
            int row = m0 + wm0 + mi * 16 + cr + j;
            float4 t0, t1, t2, t3;
            if (LORA && tvec) {
                const float* tp = tvec + (size_t)row * LRANK;
                t0 = *(const float4*)(tp + 0);  t1 = *(const float4*)(tp + 4);
                t2 = *(const float4*)(tp + 8);  t3 = *(const float4*)(tp + 12);
            }
            #pragma unroll
            for (int ni = 0; ni < 4; ++ni) {
                int col = n0 + wn0 + ni * 16 + cc;
                float r = acc[mi][ni][j] + bias[col];
                if (LORA && tvec) {
                    const float* bp = Bmat + (size_t)col * LRANK;
                    float4 b0 = *(const float4*)(bp + 0),  b1 = *(const float4*)(bp + 4);
                    float4 b2 = *(const float4*)(bp + 8),  b3 = *(const float4*)(bp + 12);
                    float d = t0.x * b0.x + t0.y * b0.y + t0.z * b0.z + t0.w * b0.w
                            + t1.x * b1.x + t1.y * b1.y + t1.z * b1.z + t1.w * b1.w
                            + t2.x * b2.x + t2.y * b2.y + t2.z * b2.z + t2.w * b2.w
                            + t3.x * b3.x + t3.y * b3.y + t3.z * b3.z + t3.w * b3.w;
                    r += LORA_SC * d;
                }
                u16 rb = f2bf(r);
                qkv_bf[(size_t)row * QKVLD + col] = rb;
                if (vrange) {
                    int vcol = col - 2 * DIM;
                    int hh = vcol >> 6, dd = vcol & 63;
                    int bb = row >> 8, kpos = row & 255;
                    vT[((size_t)(bb * NH + hh) * HDIM + dd) * SEQ + kpos] = rb;
                }
            }
        }
    }
}

// ============ fused attention ============
// grid (4 q-tiles, ZB). block = 256 thr (4 waves, 16 q-rows each).
// LDS: KV buf 256x64 (32KB, K then V^T restaged) + P buf 64x256 (32KB).
__device__ __forceinline__ int lds256_idx(int r, int col) {
    int sub = col >> 6, inner = col & 63;
    return r * 256 + sub * 64 + ((((inner >> 3) ^ (r & 7))) << 3) + (inner & 7);
}
__device__ __forceinline__ short8 frag_read256(const u16* base, int r, int kk, int kg) {
    int col = kk * 32 + kg * 8;
    int sub = col >> 6, slot = (col & 63) >> 3;
    return *(const short8*)(base + r * 256 + sub * 64 + ((slot ^ (r & 7)) << 3));
}

__global__ __launch_bounds__(256) void attn_fused(
    const u16* __restrict__ qkv_bf, const u16* __restrict__ vT,
    const int* __restrict__ mask, u16* __restrict__ o_bf) {
    __shared__ u16 lds[256 * 64 + 64 * 256];
    u16* KV = lds;
    u16* P = lds + 256 * 64;
    int qt = blockIdx.x, z = blockIdx.y;
    int b = z / NH, h = z % NH;
    int t = threadIdx.x, lane = t & 63, w = t >> 6;
    int cc = lane & 15, q4 = lane >> 4;

    // mask bias in regs (cols ni*16+cc)
    float mb[16];
    #pragma unroll
    for (int ni = 0; ni < 16; ++ni)
        mb[ni] = (1.0f - (float)mask[b * SEQ + ni * 16 + cc]) * -1e9f;

    // Q fragments (row = lane&15 within wave's 16 rows)
    int qrow = b * SEQ + qt * 64 + w * 16 + cc;
    const u16* qp = qkv_bf + (size_t)qrow * QKVLD + h * HDIM + q4 * 8;
    short8 qa0 = *(const short8*)(qp);
    short8 qa1 = *(const short8*)(qp + 32);

    // stage K (rows = kpos 0..255, cols = d)
    stage_tile<256>(qkv_bf + (size_t)(b * SEQ) * QKVLD + DIM + h * HDIM, QKVLD, KV, w, lane);
    __syncthreads();

    // QK^T: S[16 rows][256 cols] per wave
    floatx4 s[16];
    #pragma unroll
    for (int ni = 0; ni < 16; ++ni) s[ni] = (floatx4){0.f, 0.f, 0.f, 0.f};
    #pragma unroll
    for (int kk = 0; kk < 2; ++kk) {
        short8 qa = kk == 0 ? qa0 : qa1;
        #pragma unroll
        for (int ni = 0; ni < 16; ++ni) {
            short8 kf = frag_read(KV, ni * 16 + cc, kk * 4 + q4);
            s[ni] = __builtin_amdgcn_mfma_f32_16x16x32_bf16(qa, kf, s[ni], 0, 0, 0);
        }
    }

    // softmax over the 256 cols of each of this lane-quarter's 4 rows
    float pv[16][4];
    float mrow[4] = {-1e30f, -1e30f, -1e30f, -1e30f};
    #pragma unroll
    for (int ni = 0; ni < 16; ++ni)
        #pragma unroll
        for (int j = 0; j < 4; ++j) {
            float v = s[ni][j] * 0.125f + mb[ni];
            pv[ni][j] = v;
            mrow[j] = fmaxf(mrow[j], v);
        }
    #pragma unroll
    for (int o = 1; o < 16; o <<= 1)
        #pragma unroll
        for (int j = 0; j < 4; ++j) mrow[j] = fmaxf(mrow[j], __shfl_xor(mrow[j], o));
    float srow[4] = {0.f, 0.f, 0.f, 0.f};
    #pragma unroll
    for (int ni = 0; ni < 16; ++ni)
        #pragma unroll
        for (int j = 0; j < 4; ++j) {
            float e = __expf(pv[ni][j] - mrow[j]);
            pv[ni][j] = e;
            srow[j] += e;
        }
    #pragma unroll
    for (int o = 1; o < 16; o <<= 1)
        #pragma unroll
        for (int j = 0; j < 4; ++j) srow[j] += __shfl_xor(srow[j], o);
    float inv[4];
    #pragma unroll
    for (int j = 0; j < 4; ++j) inv[j] = 1.0f / srow[j];

    // write P (bf16) into this wave's LDS region
    u16* Pw = P + w * 16 * 256;
    #pragma unroll
    for (int ni = 0; ni < 16; ++ni)
        #pragma unroll
        for (int j = 0; j < 4; ++j)
            Pw[lds256_idx(q4 * 4 + j, ni * 16 + cc)] = f2bf(pv[ni][j] * inv[j]);
    __syncthreads();   // all waves done reading K + writing P

    // restage V^T (rows = d 0..63, cols = kpos 0..255) over the K buffer
    {
        const u16* vz = vT + (size_t)z * HDIM * SEQ;
        int rin = lane >> 3, slot = lane & 7;
        #pragma unroll
        for (int c0 = 0; c0 < 32; c0 += 4) {
            int c = c0 + w;
            int vrow = c * 8 + rin;
            int d = vrow >> 2, sub = vrow & 3;
            const u16* src = vz + d * 256 + sub * 64 + (((slot ^ (d & 7))) << 3);
            __builtin_amdgcn_global_load_lds(
                (const __attribute__((address_space(1))) unsigned int*)src,
                (__attribute__((address_space(3))) unsigned int*)(KV + c * 512 + lane * 8),
                16, 0, 0);
        }
    }
    __syncthreads();

    // PV: O[16 rows][64 cols] per wave
    floatx4 oa[4];
    #pragma unroll
    for (int ni = 0; ni < 4; ++ni) oa[ni] = (floatx4){0.f, 0.f, 0.f, 0.f};
    #pragma unroll
    for (int kk = 0; kk < 8; ++kk) {
        short8 pf = frag_read256(Pw, cc, kk, q4);
        #pragma unroll
        for (int ni = 0; ni < 4; ++ni) {
            short8 vf = frag_read256(KV, ni * 16 + cc, kk, q4);
            oa[ni] = __builtin_amdgcn_mfma_f32_16x16x32_bf16(pf, vf, oa[ni], 0, 0, 0);
        }
    }
    #pragma unroll
    for (int ni = 0; ni < 4; ++ni)
        #pragma unroll
        for (int j = 0; j < 4; ++j) {
            int m = b * SEQ + qt * 64 + w * 16 + q4 * 4 + j;
            o_bf[(size_t)m * DIM + h * HDIM + ni * 16 + cc] = f2bf(oa[ni][j]);
        }
}

// ============ LoRA t-vectors: t[m][16] = h[m][:] @ A[task]^T ============
__global__ __launch_bounds__(256) void lora_t_kernel(
    const float* __restrict__ h, const float* __restrict__ qA,
    const float* __restrict__ vA, const int* __restrict__ task,
    int layer, float* __restrict__ tq, float* __restrict__ tv) {
    int which = blockIdx.y;
    const float* Ab = which ? vA : qA;
    float* tout = which ? tv : tq;
    int m0 = blockIdx.x * 64;
    int tk = task[m0 >> 8];
    const float* Ap = Ab + ((size_t)tk * LAYERS + layer) * LRANK * DIM;
    int t = threadIdx.x;
    int row = t & 63, rb = t >> 6;
    float s[4] = {0.f, 0.f, 0.f, 0.f};
    const float* hrow = h + (size_t)(m0 + row) * DIM;
    for (int d = 0; d < DIM; d += 4) {
        float4 hv = *(const float4*)&hrow[d];
        #pragma unroll
        for (int i = 0; i < 4; ++i) {
            float4 av = *(const float4*)&Ap[(size_t)(rb + i * 4) * DIM + d];
            s[i] += hv.x * av.x + hv.y * av.y + hv.z * av.z + hv.w * av.w;
        }
    }
    #pragma unroll
    for (int i = 0; i < 4; ++i)
        tout[(size_t)(m0 + row) * LRANK + rb + i * 4] = s[i];
}

// ============ router head ============
__global__ __launch_bounds__(256) void router_kernel(
    const float* __restrict__ hb, const float* __restrict__ W1,
    const float* __restrict__ b1, const float* __restrict__ W2,
    const float* __restrict__ b2, const float* __restrict__ temp,
    float* __restrict__ out_logits, int* __restrict__ task) {
    int b = blockIdx.x;
    int t = threadIdx.x;
    __shared__ float cls[DIM];
    __shared__ float y1[DIM];
    __shared__ float red[3][4];
    #pragma unroll
    for (int j = 0; j < 3; ++j) cls[t + j * 256] = hb[(size_t)(b * SEQ) * DIM + t + j * 256];
    __syncthreads();
    #pragma unroll
    for (int j = 0; j < 3; ++j) {
        int col = t + j * 256;
        float s = b1[col];
        for (int d = 0; d < DIM; ++d) s += cls[d] * W1[(size_t)d * DIM + col];
        y1[col] = fmaxf(s, 0.0f);
    }
    __syncthreads();
    float p[3] = {0.f, 0.f, 0.f};
    #pragma unroll
    for (int j = 0; j < 3; ++j) {
        int col = t + j * 256;
        float y = y1[col];
        p[0] += y * W2[col * 3 + 0];
        p[1] += y * W2[col * 3 + 1];
        p[2] += y * W2[col * 3 + 2];
    }
    #pragma unroll
    for (int o = 32; o; o >>= 1) {
        p[0] += __shfl_down(p[0], o);
        p[1] += __shfl_down(p[1], o);
        p[2] += __shfl_down(p[2], o);
    }
    int w = t >> 6;
    if ((t & 63) == 0) { red[0][w] = p[0]; red[1][w] = p[1]; red[2][w] = p[2]; }
    __syncthreads();
    if (t == 0) {
        float tt = fmaxf(temp[0], 0.05f);
        float l[3];
        #pragma unroll
        for (int c = 0; c < 3; ++c) {
            l[c] = (red[c][0] + red[c][1] + red[c][2] + red[c][3] + b2[c]) / tt;
            out_logits[b * 3 + c] = l[c];
        }
        int bt = 0; float bv = l[0];
        if (l[1] > bv) { bv = l[1]; bt = 1; }
        if (l[2] > bv) { bv = l[2]; bt = 2; }
        task[b] = bt;
    }
}

// ============ final classifier head ============
__global__ __launch_bounds__(256) void cls_kernel(
    const float* __restrict__ ha, const float* __restrict__ cW1,
    const float* __restrict__ cb1, const float* __restrict__ cW2,
    const float* __restrict__ cb2, const int* __restrict__ task,
    float* __restrict__ out) {
    int b = blockIdx.x;
    int t = threadIdx.x;
    int tk = task[b];
    const float* W1 = cW1 + (size_t)tk * DIM * DIM;
    const float* b1 = cb1 + tk * DIM;
    const float* W2 = cW2 + (size_t)tk * DIM * 2;
    const float* b2 = cb2 + tk * 2;
    __shared__ float f[DIM];
    __shared__ float y1[DIM];
    __shared__ float red[2][4];
    #pragma unroll
    for (int j = 0; j < 3; ++j) f[t + j * 256] = ha[(size_t)(b * SEQ) * DIM + t + j * 256];
    __syncthreads();
    #pragma unroll
    for (int j = 0; j < 3; ++j) {
        int col = t + j * 256;
        float s = b1[col];
        for (int d = 0; d < DIM; ++d) s += f[d] * W1[(size_t)d * DIM + col];
        y1[col] = tanhf(s);
    }
    __syncthreads();
    float p[2] = {0.f, 0.f};
    #pragma unroll
    for (int j = 0; j < 3; ++j) {
        int col = t + j * 256;
        float y = y1[col];
        p[0] += y * W2[col * 2 + 0];
        p[1] += y * W2[col * 2 + 1];
    }
    #pragma unroll
    for (int o = 32; o; o >>= 1) {
        p[0] += __shfl_down(p[0], o);
        p[1] += __shfl_down(p[1], o);
    }
    int w = t >> 6;
    if ((t & 63) == 0) { red[0][w] = p[0]; red[1][w] = p[1]; }
    __syncthreads();
    if (t == 0) {
        #pragma unroll
        for (int c = 0; c < 2; ++c)
            out[b * 2 + c] = red[c][0] + red[c][1] + red[c][2] + red[c][3] + b2[c];
    }
}

extern "C" void kernel_launch(void* const* d_in, const int* in_sizes, int n_in,
                              void* d_out, int out_size, void* d_ws, size_t ws_size,
                              hipStream_t stream) {
    (void)in_sizes; (void)n_in; (void)out_size; (void)ws_size;
    const int*   ids   = (const int*)d_in[0];
    const int*   mask  = (const int*)d_in[1];
    const float* wemb  = (const float*)d_in[2];
    const float* pemb  = (const float*)d_in[3];
    const float* emb_g = (const float*)d_in[4];
    const float* emb_b = (const float*)d_in[5];
    const float* Wq    = (const float*)d_in[6];
    const float* Wk    = (const float*)d_in[7];
    const float* Wv    = (const float*)d_in[8];
    const float* Wo    = (const float*)d_in[9];
    const float* Wi    = (const float*)d_in[10];
    const float* Wo2   = (const float*)d_in[11];
    const float* bq    = (const float*)d_in[12];
    const float* bk    = (const float*)d_in[13];
    const float* bv    = (const float*)d_in[14];
    const float* bo    = (const float*)d_in[15];
    const float* bi    = (const float*)d_in[16];
    const float* bo2   = (const float*)d_in[17];
    const float* g1    = (const float*)d_in[18];
    const float* b1    = (const float*)d_in[19];
    const float* g2    = (const float*)d_in[20];
    const float* b2    = (const float*)d_in[21];
    const float* rW1   = (const float*)d_in[22];
    const float* rb1   = (const float*)d_in[23];
    const float* rW2   = (const float*)d_in[24];
    const float* rb2   = (const float*)d_in[25];
    const float* temp  = (const float*)d_in[26];
    const float* qA    = (const float*)d_in[27];
    const float* qB    = (const float*)d_in[28];
    const float* vA    = (const float*)d_in[29];
    const float* vB    = (const float*)d_in[30];
    const float* cW1   = (const float*)d_in[31];
    const float* cb1   = (const float*)d_in[32];
    const float* cW2   = (const float*)d_in[33];
    const float* cb2   = (const float*)d_in[34];
    float* out = (float*)d_out;

    const size_t MD = (size_t)MTOK * DIM;
    char* p = (char*)d_ws;
    auto alloc = [&](size_t bytes) { char* r = p; p += (bytes + 255) & ~(size_t)255; return r; };
    float* h      = (float*)alloc(MD * 4);
    float* h2     = (float*)alloc(MD * 4);
    float* h0     = (float*)alloc(MD * 4);
    u16* h_bf   = (u16*)alloc(MD * 2);
    u16* h0_bf  = (u16*)alloc(MD * 2);
    u16* o_bf   = (u16*)alloc(MD * 2);
    u16* qkv_bf = (u16*)alloc((size_t)MTOK * QKVLD * 2);
    u16* ffb_bf = (u16*)alloc((size_t)MTOK * FFDIM * 2);
    u16* vT     = (u16*)alloc((size_t)ZB * HDIM * SEQ * 2);
    float* tq   = (float*)alloc((size_t)MTOK * LRANK * 4);
    float* tv   = (float*)alloc((size_t)MTOK * LRANK * 4);
    float* bqkv = (float*)alloc((size_t)LAYERS * QKVLD * 4);
    int* task   = (int*)alloc(256);
    u16* WqkvT  = (u16*)alloc((size_t)LAYERS * QKVLD * DIM * 2);
    u16* WoT    = (u16*)alloc((size_t)LAYERS * DIM * DIM * 2);
    u16* WiT    = (u16*)alloc((size_t)LAYERS * FFDIM * DIM * 2);
    u16* Wo2T   = (u16*)alloc((size_t)LAYERS * DIM * FFDIM * 2);

    dim3 blk(256);
    // --- weight prep (bf16, [N][K]) ---
    w_transpose<<<dim3(24, 24, LAYERS), blk, 0, stream>>>(Wq, (size_t)DIM * DIM, WqkvT, (size_t)QKVLD * DIM, DIM, DIM, 0);
    w_transpose<<<dim3(24, 24, LAYERS), blk, 0, stream>>>(Wk, (size_t)DIM * DIM, WqkvT, (size_t)QKVLD * DIM, DIM, DIM, DIM);
    w_transpose<<<dim3(24, 24, LAYERS), blk, 0, stream>>>(Wv, (size_t)DIM * DIM, WqkvT, (size_t)QKVLD * DIM, DIM, DIM, 2 * DIM);
    w_transpose<<<dim3(24, 24, LAYERS), blk, 0, stream>>>(Wo, (size_t)DIM * DIM, WoT, (size_t)DIM * DIM, DIM, DIM, 0);
    w_transpose<<<dim3(96, 24, LAYERS), blk, 0, stream>>>(Wi, (size_t)DIM * FFDIM, WiT, (size_t)FFDIM * DIM, FFDIM, DIM, 0);
    w_transpose<<<dim3(24, 96, LAYERS), blk, 0, stream>>>(Wo2, (size_t)FFDIM * DIM, Wo2T, (size_t)DIM * FFDIM, DIM, FFDIM, 0);
    build_bqkv<<<LAYERS, blk, 0, stream>>>(bq, bk, bv, bqkv);

    embed_ln_kernel<<<MTOK, blk, 0, stream>>>(ids, wemb, pemb, emb_g, emb_b, h0, h0_bf);

    for (int pass = 0; pass < 2; ++pass) {
        hipMemcpyAsync(h, h0, MD * 4, hipMemcpyDeviceToDevice, stream);
        hipMemcpyAsync(h_bf, h0_bf, MD * 2, hipMemcpyDeviceToDevice, stream);
        for (int l = 0; l < LAYERS; ++l) {
            const u16* WqkvT_l = WqkvT + (size_t)l * QKVLD * DIM;
            const u16* WoT_l   = WoT   + (size_t)l * DIM * DIM;
            const u16* WiT_l   = WiT   + (size_t)l * FFDIM * DIM;
            const u16* Wo2T_l  = Wo2T  + (size_t)l * DIM * FFDIM;
            const float* bqkv_l = bqkv + (size_t)l * QKVLD;
            const float* bo_l  = bo  + (size_t)l * DIM;
            const float* bi_l  = bi  + (size_t)l * FFDIM;
            const float* bo2_l = bo2 + (size_t)l * DIM;
            const float* g1_l  = g1  + (size_t)l * DIM;
            const float* b1_l  = b1  + (size_t)l * DIM;
            const float* g2_l  = g2  + (size_t)l * DIM;
            const float* b2_l  = b2  + (size_t)l * DIM;

            if (pass == 0) {
                gemm_qkv<0><<<dim3(QKVLD / 128, MTOK / 128), blk, 0, stream>>>(
                    h_bf, WqkvT_l, bqkv_l, qkv_bf, vT,
                    nullptr, nullptr, nullptr, nullptr, nullptr, l);
            } else {
                lora_t_kernel<<<dim3(MTOK / 64, 2), blk, 0, stream>>>(h, qA, vA, task, l, tq, tv);
                gemm_qkv<1><<<dim3(QKVLD / 128, MTOK / 128), blk, 0, stream>>>(
                    h_bf, WqkvT_l, bqkv_l, qkv_bf, vT,
                    tq, tv, qB, vB, task, l);
            }
            attn_fused<<<dim3(SEQ / 64, ZB), blk, 0, stream>>>(qkv_bf, vT, mask, o_bf);
            gemm_mfma<64, 128, 0, 0><<<dim3(DIM / 128, MTOK / 64), blk, 0, stream>>>(
                o_bf, DIM, WoT_l, DIM, bo_l, h2, nullptr, DIM, DIM);
            add_ln_kernel<<<MTOK, blk, 0, stream>>>(h, h2, g1_l, b1_l, h_bf);
            gemm_mfma<128, 128, 1, 1><<<dim3(FFDIM / 128, MTOK / 128), blk, 0, stream>>>(
                h_bf, DIM, WiT_l, DIM, bi_l, nullptr, ffb_bf, FFDIM, DIM);
            gemm_mfma<64, 128, 0, 0><<<dim3(DIM / 128, MTOK / 64), blk, 0, stream>>>(
                ffb_bf, FFDIM, Wo2T_l, FFDIM, bo2_l, h2, nullptr, DIM, FFDIM);
            add_ln_kernel<<<MTOK, blk, 0, stream>>>(h, h2, g2_l, b2_l, h_bf);
        }
        if (pass == 0) {
            router_kernel<<<BATCH, blk, 0, stream>>>(h, rW1, rb1, rW2, rb2, temp, out, task);
        } else {
            cls_kernel<<<BATCH, blk, 0, stream>>>(h, cW1, cb1, cW2, cb2, task, out + BATCH * TASKS);
        }
    }
}

// Round 4
// 4354.094 us; speedup vs baseline: 3.6754x; 1.0675x over previous
//
#include <hip/hip_runtime.h>
#include <math.h>

#define DIM 768
#define LAYERS 12
#define NH 12
#define HDIM 64
#define FFDIM 3072
#define SEQ 256
#define BATCH 8
#define MTOK (BATCH*SEQ)   // 2048
#define TASKS 3
#define LRANK 16
#define LORA_SC 2.0f
#define QKVLD 2304
#define ZB (BATCH*NH)      // 96

typedef unsigned short u16;
typedef __attribute__((ext_vector_type(8))) short short8;
typedef __attribute__((ext_vector_type(4))) float floatx4;
typedef __attribute__((ext_vector_type(4))) unsigned short u16x4;

__device__ __forceinline__ u16 f2bf(float f) {
    unsigned int u = __float_as_uint(f);
    u = (u + 0x7fff + ((u >> 16) & 1)) >> 16;
    return (u16)u;
}

__device__ __forceinline__ float geluf(float x) {
    float u = 0.7978845608028654f * (x + 0.044715f * x * x * x);
    u = fminf(fmaxf(u, -15.f), 15.f);
    float e = __expf(2.f * u);
    float th = (e - 1.f) / (e + 1.f);
    return 0.5f * x * (1.f + th);
}

__device__ __forceinline__ float block_sum256(float v, volatile float* sb4) {
    #pragma unroll
    for (int o = 32; o; o >>= 1) v += __shfl_down(v, o);
    int w = threadIdx.x >> 6;
    if ((threadIdx.x & 63) == 0) sb4[w] = v;
    __syncthreads();
    float total = sb4[0] + sb4[1] + sb4[2] + sb4[3];
    __syncthreads();
    return total;
}

// XCD-aware bijective block swizzle (nwg divisible by 8 at all call sites)
__device__ __forceinline__ void xcd_map(int* bx, int* by) {
    int gx = gridDim.x;
    int nwg = gx * gridDim.y;
    int orig = blockIdx.y * gx + blockIdx.x;
    int swz = (orig & 7) * (nwg >> 3) + (orig >> 3);
    *bx = swz % gx; *by = swz / gx;
}

// ============ weight transpose fp32 [K][N] -> bf16 [row_off+N][K], 64x64 ============
__global__ __launch_bounds__(256) void w_transpose64(
    const float* __restrict__ src, size_t src_ls,
    u16* __restrict__ dst, size_t dst_ls, int N, int dstld, int row_off) {
    __shared__ float tile[64][65];
    int l = blockIdx.z;
    int k0 = blockIdx.y * 64, n0 = blockIdx.x * 64;
    int t = threadIdx.x;
    int r = t >> 4, c4 = (t & 15) * 4;
    const float* s = src + (size_t)l * src_ls + (size_t)k0 * N + n0;
    #pragma unroll
    for (int i = 0; i < 4; ++i) {
        float4 v = *(const float4*)&s[(size_t)(r + i * 16) * N + c4];
        tile[r + i * 16][c4 + 0] = v.x; tile[r + i * 16][c4 + 1] = v.y;
        tile[r + i * 16][c4 + 2] = v.z; tile[r + i * 16][c4 + 3] = v.w;
    }
    __syncthreads();
    u16* d = dst + (size_t)l * dst_ls;
    #pragma unroll
    for (int i = 0; i < 4; ++i) {
        int n = r + i * 16;
        u16x4 o;
        o[0] = f2bf(tile[c4 + 0][n]); o[1] = f2bf(tile[c4 + 1][n]);
        o[2] = f2bf(tile[c4 + 2][n]); o[3] = f2bf(tile[c4 + 3][n]);
        *(u16x4*)&d[(size_t)(row_off + n0 + n) * dstld + k0 + c4] = o;
    }
}

__global__ __launch_bounds__(256) void build_bqkv(
    const float* __restrict__ bq, const float* __restrict__ bk,
    const float* __restrict__ bv, float* __restrict__ bqkv) {
    int l = blockIdx.x;
    for (int i = threadIdx.x; i < QKVLD; i += 256) {
        float v = i < DIM ? bq[l * DIM + i]
                : (i < 2 * DIM ? bk[l * DIM + i - DIM] : bv[l * DIM + i - 2 * DIM]);
        bqkv[(size_t)l * QKVLD + i] = v;
    }
}

// ============ embedding + LN (fp32 + bf16 out) ============
__global__ __launch_bounds__(256) void embed_ln_kernel(
    const int* __restrict__ ids, const float* __restrict__ wemb,
    const float* __restrict__ pemb, const float* __restrict__ g,
    const float* __restrict__ bb, float* __restrict__ out, u16* __restrict__ out_bf) {
    __shared__ float sb[4];
    int m = blockIdx.x;
    int s = m & (SEQ - 1);
    int id = ids[m];
    int t = threadIdx.x;
    float x[3];
    float sum = 0.f;
    #pragma unroll
    for (int j = 0; j < 3; ++j) {
        int d = t + j * 256;
        x[j] = wemb[(size_t)id * DIM + d] + pemb[(size_t)(s + 2) * DIM + d];
        sum += x[j];
    }
    float mean = block_sum256(sum, sb) * (1.0f / DIM);
    float vs = 0.f;
    #pragma unroll
    for (int j = 0; j < 3; ++j) { float c = x[j] - mean; vs += c * c; }
    float var = block_sum256(vs, sb) * (1.0f / DIM);
    float rstd = rsqrtf(var + 1e-5f);
    #pragma unroll
    for (int j = 0; j < 3; ++j) {
        int d = t + j * 256;
        float r = (x[j] - mean) * rstd * g[d] + bb[d];
        out[(size_t)m * DIM + d] = r;
        out_bf[(size_t)m * DIM + d] = f2bf(r);
    }
}

// ============ residual add + LN in place, + bf16 out ============
__global__ __launch_bounds__(256) void add_ln_kernel(
    float* __restrict__ h, const float* __restrict__ proj,
    const float* __restrict__ g, const float* __restrict__ bb, u16* __restrict__ h_bf) {
    __shared__ float sb[4];
    int m = blockIdx.x;
    int t = threadIdx.x;
    float x[3];
    float sum = 0.f;
    #pragma unroll
    for (int j = 0; j < 3; ++j) {
        int d = t + j * 256;
        x[j] = h[(size_t)m * DIM + d] + proj[(size_t)m * DIM + d];
        sum += x[j];
    }
    float mean = block_sum256(sum, sb) * (1.0f / DIM);
    float vs = 0.f;
    #pragma unroll
    for (int j = 0; j < 3; ++j) { float c = x[j] - mean; vs += c * c; }
    float var = block_sum256(vs, sb) * (1.0f / DIM);
    float rstd = rsqrtf(var + 1e-5f);
    #pragma unroll
    for (int j = 0; j < 3; ++j) {
        int d = t + j * 256;
        float r = (x[j] - mean) * rstd * g[d] + bb[d];
        h[(size_t)m * DIM + d] = r;
        h_bf[(size_t)m * DIM + d] = f2bf(r);
    }
}

// ============ MFMA GEMM core ============
template<int ROWS>
__device__ __forceinline__ void stage_tile(const u16* srcbase, int ldk,
                                           u16* ldsbase, int wave, int lane) {
    int rin = lane >> 3, slot = lane & 7;
    #pragma unroll
    for (int c0 = 0; c0 < ROWS / 8; c0 += 4) {
        int c = c0 + wave;
        int r = c * 8 + rin;
        int scol = ((slot ^ (r & 7)) << 3);
        const u16* src = srcbase + (size_t)r * ldk + scol;
        __builtin_amdgcn_global_load_lds(
            (const __attribute__((address_space(1))) unsigned int*)src,
            (__attribute__((address_space(3))) unsigned int*)(ldsbase + (size_t)c * 512 + lane * 8),
            16, 0, 0);
    }
}

__device__ __forceinline__ short8 frag_read(const u16* ldsbase, int r, int s) {
    return *(const short8*)(ldsbase + r * 64 + (((s ^ (r & 7)) << 3)));
}

template<int BM, int BN>
__device__ __forceinline__ void gemm_core(
    const u16* __restrict__ A, int lda, const u16* __restrict__ B, int ldb,
    int K, int m0, int n0, u16* lds, floatx4 (&acc)[BM / 32][BN / 32]) {
    u16* As = lds;
    u16* Bs = lds + BM * 64;
    int t = threadIdx.x, lane = t & 63, wave = t >> 6;
    int wr = wave >> 1, wc = wave & 1;
    constexpr int FM = BM / 32, FN = BN / 32;
    int wm0 = wr * (BM / 2), wn0 = wc * (BN / 2);
    #pragma unroll
    for (int i = 0; i < FM; ++i)
        #pragma unroll
        for (int j = 0; j < FN; ++j)
            acc[i][j] = (floatx4){0.f, 0.f, 0.f, 0.f};
    int lr = lane & 15, kg = lane >> 4;
    for (int k0 = 0; k0 < K; k0 += 64) {
        stage_tile<BM>(A + (size_t)m0 * lda + k0, lda, As, wave, lane);
        stage_tile<BN>(B + (size_t)n0 * ldb + k0, ldb, Bs, wave, lane);
        __syncthreads();
        #pragma unroll
        for (int kk = 0; kk < 2; ++kk) {
            short8 af[FM], bfr[FN];
            #pragma unroll
            for (int mi = 0; mi < FM; ++mi)
                af[mi] = frag_read(As, wm0 + mi * 16 + lr, kk * 4 + kg);
            #pragma unroll
            for (int ni = 0; ni < FN; ++ni)
                bfr[ni] = frag_read(Bs, wn0 + ni * 16 + lr, kk * 4 + kg);
            #pragma unroll
            for (int mi = 0; mi < FM; ++mi)
                #pragma unroll
                for (int ni = 0; ni < FN; ++ni)
                    acc[mi][ni] = __builtin_amdgcn_mfma_f32_16x16x32_bf16(
                        af[mi], bfr[ni], acc[mi][ni], 0, 0, 0);
        }
        __syncthreads();
    }
}

// ---- standard GEMM kernel ----
template<int BM, int BN, int ACT, int OUTMODE>   // OUTMODE: 0=f32, 1=bf16
__global__ __launch_bounds__(256) void gemm_mfma(
    const u16* __restrict__ A, int lda, const u16* __restrict__ B, int ldb,
    const float* __restrict__ bias, float* __restrict__ Cf, u16* __restrict__ Cb,
    int ldc, int K) {
    __shared__ u16 lds[(BM + BN) * 64];
    constexpr int FM = BM / 32, FN = BN / 32;
    floatx4 acc[FM][FN];
    int bx, by;
    xcd_map(&bx, &by);
    int m0 = by * BM, n0 = bx * BN;
    gemm_core<BM, BN>(A, lda, B, ldb, K, m0, n0, lds, acc);
    int t = threadIdx.x, lane = t & 63, wave = t >> 6;
    int wr = wave >> 1, wc = wave & 1;
    int wm0 = wr * (BM / 2), wn0 = wc * (BN / 2);
    int cr = (lane >> 4) * 4, cc = lane & 15;
    #pragma unroll
    for (int mi = 0; mi < FM; ++mi) {
        #pragma unroll
        for (int ni = 0; ni < FN; ++ni) {
            int col = n0 + wn0 + ni * 16 + cc;
            float bsv = bias ? bias[col] : 0.f;
            #pragma unroll
            for (int j = 0; j < 4; ++j) {
                int row = m0 + wm0 + mi * 16 + cr + j;
                float r = acc[mi][ni][j] + bsv;
                if (ACT == 1) r = geluf(r);
                if (OUTMODE == 0) Cf[(size_t)row * ldc + col] = r;
                else Cb[(size_t)row * ldc + col] = f2bf(r);
            }
        }
    }
}

// ---- QKV GEMM: bias, optional fused LoRA, bf16 out, fused vT scatter ----
template<int LORA>
__global__ __launch_bounds__(256) void gemm_qkv(
    const u16* __restrict__ A, const u16* __restrict__ Bw,
    const float* __restrict__ bias, u16* __restrict__ qkv_bf,
    u16* __restrict__ vT,
    const float* __restrict__ tq, const float* __restrict__ tv,
    const float* __restrict__ qBb, const float* __restrict__ vBb,
    const int* __restrict__ taskp, int layer) {
    __shared__ u16 lds[(128 + 128) * 64];
    floatx4 acc[4][4];
    int bx, by;
    xcd_map(&bx, &by);
    int m0 = by * 128, n0 = bx * 128;
    gemm_core<128, 128>(A, DIM, Bw, DIM, DIM, m0, n0, lds, acc);
    int t = threadIdx.x, lane = t & 63, wave = t >> 6;
    int wr = wave >> 1, wc = wave & 1;
    int wm0 = wr * 64, wn0 = wc * 64;
    int cr = (lane >> 4) * 4, cc = lane & 15;
    const float* tvec = nullptr;
    const float* Bmat = nullptr;
    if (LORA) {
        int tk = taskp[m0 >> 8];
        if (n0 < DIM) {
            tvec = tq;
            Bmat = qBb + ((size_t)tk * LAYERS + layer) * DIM * LRANK;
        } else if (n0 >= 2 * DIM) {
            tvec = tv;
            Bmat = vBb + ((size_t)tk * LAYERS + layer) * DIM * LRANK - (size_t)2 * DIM * LRANK;
        }
    }
    bool vrange = (n0 >= 2 * DIM);
    #pragma unroll
    for (int mi = 0; mi < 4; ++mi) {
        #pragma unroll
        for (int j = 0; j < 4; ++j) {
            int row = m0 + wm0 + mi * 16 + cr + j;
            float4 t0, t1, t2, t3;
            if (LORA && tvec) {
                const float* tp = tvec + (size_t)row * LRANK;
                t0 = *(const float4*)(tp + 0);  t1 = *(const float4*)(tp + 4);
                t2 = *(const float4*)(tp + 8);  t3 = *(const float4*)(tp + 12);
            }
            #pragma unroll
            for (int ni = 0; ni < 4; ++ni) {
                int col = n0 + wn0 + ni * 16 + cc;
                float r = acc[mi][ni][j] + bias[col];
                if (LORA && tvec) {
                    const float* bp = Bmat + (size_t)col * LRANK;
                    float4 b0 = *(const float4*)(bp + 0),  b1 = *(const float4*)(bp + 4);
                    float4 b2 = *(const float4*)(bp + 8),  b3 = *(const float4*)(bp + 12);
                    float d = t0.x * b0.x + t0.y * b0.y + t0.z * b0.z + t0.w * b0.w
                            + t1.x * b1.x + t1.y * b1.y + t1.z * b1.z + t1.w * b1.w
                            + t2.x * b2.x + t2.y * b2.y + t2.z * b2.z + t2.w * b2.w
                            + t3.x * b3.x + t3.y * b3.y + t3.z * b3.z + t3.w * b3.w;
                    r += LORA_SC * d;
                }
                u16 rb = f2bf(r);
                qkv_bf[(size_t)row * QKVLD + col] = rb;
                if (vrange) {
                    int vcol = col - 2 * DIM;
                    int hh = vcol >> 6, dd = vcol & 63;
                    int bb = row >> 8, kpos = row & 255;
                    vT[((size_t)(bb * NH + hh) * HDIM + dd) * SEQ + kpos] = rb;
                }
            }
        }
    }
}

// ============ fused attention ============
__device__ __forceinline__ int lds256_idx(int r, int col) {
    int sub = col >> 6, inner = col & 63;
    return r * 256 + sub * 64 + ((((inner >> 3) ^ (r & 7))) << 3) + (inner & 7);
}
__device__ __forceinline__ short8 frag_read256(const u16* base, int r, int kk, int kg) {
    int col = kk * 32 + kg * 8;
    int sub = col >> 6, slot = (col & 63) >> 3;
    return *(const short8*)(base + r * 256 + sub * 64 + ((slot ^ (r & 7)) << 3));
}

__global__ __launch_bounds__(256) void attn_fused(
    const u16* __restrict__ qkv_bf, const u16* __restrict__ vT,
    const int* __restrict__ mask, u16* __restrict__ o_bf) {
    __shared__ u16 lds[256 * 64 + 64 * 256];
    u16* KV = lds;
    u16* P = lds + 256 * 64;
    int qt = blockIdx.x, z = blockIdx.y;
    int b = z / NH, h = z % NH;
    int t = threadIdx.x, lane = t & 63, w = t >> 6;
    int cc = lane & 15, q4 = lane >> 4;

    float mb[16];
    #pragma unroll
    for (int ni = 0; ni < 16; ++ni)
        mb[ni] = (1.0f - (float)mask[b * SEQ + ni * 16 + cc]) * -1e9f;

    int qrow = b * SEQ + qt * 64 + w * 16 + cc;
    const u16* qp = qkv_bf + (size_t)qrow * QKVLD + h * HDIM + q4 * 8;
    short8 qa0 = *(const short8*)(qp);
    short8 qa1 = *(const short8*)(qp + 32);

    stage_tile<256>(qkv_bf + (size_t)(b * SEQ) * QKVLD + DIM + h * HDIM, QKVLD, KV, w, lane);
    __syncthreads();

    floatx4 s[16];
    #pragma unroll
    for (int ni = 0; ni < 16; ++ni) s[ni] = (floatx4){0.f, 0.f, 0.f, 0.f};
    #pragma unroll
    for (int kk = 0; kk < 2; ++kk) {
        short8 qa = kk == 0 ? qa0 : qa1;
        #pragma unroll
        for (int ni = 0; ni < 16; ++ni) {
            short8 kf = frag_read(KV, ni * 16 + cc, kk * 4 + q4);
            s[ni] = __builtin_amdgcn_mfma_f32_16x16x32_bf16(qa, kf, s[ni], 0, 0, 0);
        }
    }

    float pv[16][4];
    float mrow[4] = {-1e30f, -1e30f, -1e30f, -1e30f};
    #pragma unroll
    for (int ni = 0; ni < 16; ++ni)
        #pragma unroll
        for (int j = 0; j < 4; ++j) {
            float v = s[ni][j] * 0.125f + mb[ni];
            pv[ni][j] = v;
            mrow[j] = fmaxf(mrow[j], v);
        }
    #pragma unroll
    for (int o = 1; o < 16; o <<= 1)
        #pragma unroll
        for (int j = 0; j < 4; ++j) mrow[j] = fmaxf(mrow[j], __shfl_xor(mrow[j], o));
    float srow[4] = {0.f, 0.f, 0.f, 0.f};
    #pragma unroll
    for (int ni = 0; ni < 16; ++ni)
        #pragma unroll
        for (int j = 0; j < 4; ++j) {
            float e = __expf(pv[ni][j] - mrow[j]);
            pv[ni][j] = e;
            srow[j] += e;
        }
    #pragma unroll
    for (int o = 1; o < 16; o <<= 1)
        #pragma unroll
        for (int j = 0; j < 4; ++j) srow[j] += __shfl_xor(srow[j], o);
    float inv[4];
    #pragma unroll
    for (int j = 0; j < 4; ++j) inv[j] = 1.0f / srow[j];

    u16* Pw = P + w * 16 * 256;
    #pragma unroll
    for (int ni = 0; ni < 16; ++ni)
        #pragma unroll
        for (int j = 0; j < 4; ++j)
            Pw[lds256_idx(q4 * 4 + j, ni * 16 + cc)] = f2bf(pv[ni][j] * inv[j]);
    __syncthreads();

    {
        const u16* vz = vT + (size_t)z * HDIM * SEQ;
        int rin = lane >> 3, slot = lane & 7;
        #pragma unroll
        for (int c0 = 0; c0 < 32; c0 += 4) {
            int c = c0 + w;
            int vrow = c * 8 + rin;
            int d = vrow >> 2, sub = vrow & 3;
            const u16* src = vz + d * 256 + sub * 64 + (((slot ^ (d & 7))) << 3);
            __builtin_amdgcn_global_load_lds(
                (const __attribute__((address_space(1))) unsigned int*)src,
                (__attribute__((address_space(3))) unsigned int*)(KV + c * 512 + lane * 8),
                16, 0, 0);
        }
    }
    __syncthreads();

    floatx4 oa[4];
    #pragma unroll
    for (int ni = 0; ni < 4; ++ni) oa[ni] = (floatx4){0.f, 0.f, 0.f, 0.f};
    #pragma unroll
    for (int kk = 0; kk < 8; ++kk) {
        short8 pf = frag_read256(Pw, cc, kk, q4);
        #pragma unroll
        for (int ni = 0; ni < 4; ++ni) {
            short8 vf = frag_read256(KV, ni * 16 + cc, kk, q4);
            oa[ni] = __builtin_amdgcn_mfma_f32_16x16x32_bf16(pf, vf, oa[ni], 0, 0, 0);
        }
    }
    #pragma unroll
    for (int ni = 0; ni < 4; ++ni)
        #pragma unroll
        for (int j = 0; j < 4; ++j) {
            int m = b * SEQ + qt * 64 + w * 16 + q4 * 4 + j;
            o_bf[(size_t)m * DIM + h * HDIM + ni * 16 + cc] = f2bf(oa[ni][j]);
        }
}

// ============ LoRA t-vectors ============
__global__ __launch_bounds__(256) void lora_t_kernel(
    const float* __restrict__ h, const float* __restrict__ qA,
    const float* __restrict__ vA, const int* __restrict__ task,
    int layer, float* __restrict__ tq, float* __restrict__ tv) {
    int which = blockIdx.y;
    const float* Ab = which ? vA : qA;
    float* tout = which ? tv : tq;
    int m0 = blockIdx.x * 64;
    int tk = task[m0 >> 8];
    const float* Ap = Ab + ((size_t)tk * LAYERS + layer) * LRANK * DIM;
    int t = threadIdx.x;
    int row = t & 63, rb = t >> 6;
    float s[4] = {0.f, 0.f, 0.f, 0.f};
    const float* hrow = h + (size_t)(m0 + row) * DIM;
    for (int d = 0; d < DIM; d += 4) {
        float4 hv = *(const float4*)&hrow[d];
        #pragma unroll
        for (int i = 0; i < 4; ++i) {
            float4 av = *(const float4*)&Ap[(size_t)(rb + i * 4) * DIM + d];
            s[i] += hv.x * av.x + hv.y * av.y + hv.z * av.z + hv.w * av.w;
        }
    }
    #pragma unroll
    for (int i = 0; i < 4; ++i)
        tout[(size_t)(m0 + row) * LRANK + rb + i * 4] = s[i];
}

// ============ heads: stage 1 (parallel matvec y1 = act(cls@W1+b1)) ============
template<int TANH>
__global__ __launch_bounds__(256) void head1_kernel(
    const float* __restrict__ h, const float* __restrict__ W1base,
    const float* __restrict__ b1base, const int* __restrict__ taskp,
    float* __restrict__ y1) {
    int b = blockIdx.y;
    int c0 = blockIdx.x * 64;
    int tk = taskp ? taskp[b] : 0;
    const float* W1 = W1base + (size_t)tk * DIM * DIM;
    const float* b1 = b1base + (size_t)tk * DIM;
    __shared__ float cls[DIM];
    __shared__ float part[4][64];
    int t = threadIdx.x;
    for (int j = t; j < DIM; j += 256) cls[j] = h[(size_t)(b * SEQ) * DIM + j];
    __syncthreads();
    int col = c0 + (t & 63);
    int seg = t >> 6;
    float s = 0.f;
    #pragma unroll 4
    for (int d = seg * 192; d < seg * 192 + 192; ++d)
        s += cls[d] * W1[(size_t)d * DIM + col];
    part[seg][t & 63] = s;
    __syncthreads();
    if (t < 64) {
        float r = part[0][t] + part[1][t] + part[2][t] + part[3][t] + b1[c0 + t];
        y1[(size_t)b * DIM + c0 + t] = TANH ? tanhf(r) : fmaxf(r, 0.f);
    }
}

// ============ router finalize ============
__global__ __launch_bounds__(256) void router_fin(
    const float* __restrict__ y1, const float* __restrict__ W2,
    const float* __restrict__ b2, const float* __restrict__ temp,
    float* __restrict__ out_logits, int* __restrict__ task) {
    int b = blockIdx.x;
    int t = threadIdx.x;
    __shared__ float red[3][4];
    float p[3] = {0.f, 0.f, 0.f};
    #pragma unroll
    for (int j = 0; j < 3; ++j) {
        int col = t + j * 256;
        float y = y1[(size_t)b * DIM + col];
        p[0] += y * W2[col * 3 + 0];
        p[1] += y * W2[col * 3 + 1];
        p[2] += y * W2[col * 3 + 2];
    }
    #pragma unroll
    for (int o = 32; o; o >>= 1) {
        p[0] += __shfl_down(p[0], o);
        p[1] += __shfl_down(p[1], o);
        p[2] += __shfl_down(p[2], o);
    }
    int w = t >> 6;
    if ((t & 63) == 0) { red[0][w] = p[0]; red[1][w] = p[1]; red[2][w] = p[2]; }
    __syncthreads();
    if (t == 0) {
        float tt = fmaxf(temp[0], 0.05f);
        float l[3];
        #pragma unroll
        for (int c = 0; c < 3; ++c) {
            l[c] = (red[c][0] + red[c][1] + red[c][2] + red[c][3] + b2[c]) / tt;
            out_logits[b * 3 + c] = l[c];
        }
        int bt = 0; float bv = l[0];
        if (l[1] > bv) { bv = l[1]; bt = 1; }
        if (l[2] > bv) { bv = l[2]; bt = 2; }
        task[b] = bt;
    }
}

// ============ classifier finalize ============
__global__ __launch_bounds__(256) void cls_fin(
    const float* __restrict__ y1, const float* __restrict__ cW2,
    const float* __restrict__ cb2, const int* __restrict__ task,
    float* __restrict__ out) {
    int b = blockIdx.x;
    int t = threadIdx.x;
    int tk = task[b];
    const float* W2 = cW2 + (size_t)tk * DIM * 2;
    const float* b2 = cb2 + tk * 2;
    __shared__ float red[2][4];
    float p[2] = {0.f, 0.f};
    #pragma unroll
    for (int j = 0; j < 3; ++j) {
        int col = t + j * 256;
        float y = y1[(size_t)b * DIM + col];
        p[0] += y * W2[col * 2 + 0];
        p[1] += y * W2[col * 2 + 1];
    }
    #pragma unroll
    for (int o = 32; o; o >>= 1) {
        p[0] += __shfl_down(p[0], o);
        p[1] += __shfl_down(p[1], o);
    }
    int w = t >> 6;
    if ((t & 63) == 0) { red[0][w] = p[0]; red[1][w] = p[1]; }
    __syncthreads();
    if (t == 0) {
        #pragma unroll
        for (int c = 0; c < 2; ++c)
            out[b * 2 + c] = red[c][0] + red[c][1] + red[c][2] + red[c][3] + b2[c];
    }
}

extern "C" void kernel_launch(void* const* d_in, const int* in_sizes, int n_in,
                              void* d_out, int out_size, void* d_ws, size_t ws_size,
                              hipStream_t stream) {
    (void)in_sizes; (void)n_in; (void)out_size; (void)ws_size;
    const int*   ids   = (const int*)d_in[0];
    const int*   mask  = (const int*)d_in[1];
    const float* wemb  = (const float*)d_in[2];
    const float* pemb  = (const float*)d_in[3];
    const float* emb_g = (const float*)d_in[4];
    const float* emb_b = (const float*)d_in[5];
    const float* Wq    = (const float*)d_in[6];
    const float* Wk    = (const float*)d_in[7];
    const float* Wv    = (const float*)d_in[8];
    const float* Wo    = (const float*)d_in[9];
    const float* Wi    = (const float*)d_in[10];
    const float* Wo2   = (const float*)d_in[11];
    const float* bq    = (const float*)d_in[12];
    const float* bk    = (const float*)d_in[13];
    const float* bv    = (const float*)d_in[14];
    const float* bo    = (const float*)d_in[15];
    const float* bi    = (const float*)d_in[16];
    const float* bo2   = (const float*)d_in[17];
    const float* g1    = (const float*)d_in[18];
    const float* b1    = (const float*)d_in[19];
    const float* g2    = (const float*)d_in[20];
    const float* b2    = (const float*)d_in[21];
    const float* rW1   = (const float*)d_in[22];
    const float* rb1   = (const float*)d_in[23];
    const float* rW2   = (const float*)d_in[24];
    const float* rb2   = (const float*)d_in[25];
    const float* temp  = (const float*)d_in[26];
    const float* qA    = (const float*)d_in[27];
    const float* qB    = (const float*)d_in[28];
    const float* vA    = (const float*)d_in[29];
    const float* vB    = (const float*)d_in[30];
    const float* cW1   = (const float*)d_in[31];
    const float* cb1   = (const float*)d_in[32];
    const float* cW2   = (const float*)d_in[33];
    const float* cb2   = (const float*)d_in[34];
    float* out = (float*)d_out;

    const size_t MD = (size_t)MTOK * DIM;
    char* p = (char*)d_ws;
    auto alloc = [&](size_t bytes) { char* r = p; p += (bytes + 255) & ~(size_t)255; return r; };
    float* h      = (float*)alloc(MD * 4);
    float* h2     = (float*)alloc(MD * 4);
    float* h0     = (float*)alloc(MD * 4);
    u16* h_bf   = (u16*)alloc(MD * 2);
    u16* h0_bf  = (u16*)alloc(MD * 2);
    u16* o_bf   = (u16*)alloc(MD * 2);
    u16* qkv_bf = (u16*)alloc((size_t)MTOK * QKVLD * 2);
    u16* ffb_bf = (u16*)alloc((size_t)MTOK * FFDIM * 2);
    u16* vT     = (u16*)alloc((size_t)ZB * HDIM * SEQ * 2);
    float* tq   = (float*)alloc((size_t)MTOK * LRANK * 4);
    float* tv   = (float*)alloc((size_t)MTOK * LRANK * 4);
    float* bqkv = (float*)alloc((size_t)LAYERS * QKVLD * 4);
    float* y1   = (float*)alloc((size_t)BATCH * DIM * 4);
    int* task   = (int*)alloc(256);
    u16* WqkvT  = (u16*)alloc((size_t)LAYERS * QKVLD * DIM * 2);
    u16* WoT    = (u16*)alloc((size_t)LAYERS * DIM * DIM * 2);
    u16* WiT    = (u16*)alloc((size_t)LAYERS * FFDIM * DIM * 2);
    u16* Wo2T   = (u16*)alloc((size_t)LAYERS * DIM * FFDIM * 2);

    dim3 blk(256);
    // --- weight prep (bf16, [N][K]) ---
    w_transpose64<<<dim3(12, 12, LAYERS), blk, 0, stream>>>(Wq, (size_t)DIM * DIM, WqkvT, (size_t)QKVLD * DIM, DIM, DIM, 0);
    w_transpose64<<<dim3(12, 12, LAYERS), blk, 0, stream>>>(Wk, (size_t)DIM * DIM, WqkvT, (size_t)QKVLD * DIM, DIM, DIM, DIM);
    w_transpose64<<<dim3(12, 12, LAYERS), blk, 0, stream>>>(Wv, (size_t)DIM * DIM, WqkvT, (size_t)QKVLD * DIM, DIM, DIM, 2 * DIM);
    w_transpose64<<<dim3(12, 12, LAYERS), blk, 0, stream>>>(Wo, (size_t)DIM * DIM, WoT, (size_t)DIM * DIM, DIM, DIM, 0);
    w_transpose64<<<dim3(48, 12, LAYERS), blk, 0, stream>>>(Wi, (size_t)DIM * FFDIM, WiT, (size_t)FFDIM * DIM, FFDIM, DIM, 0);
    w_transpose64<<<dim3(12, 48, LAYERS), blk, 0, stream>>>(Wo2, (size_t)FFDIM * DIM, Wo2T, (size_t)DIM * FFDIM, DIM, FFDIM, 0);
    build_bqkv<<<LAYERS, blk, 0, stream>>>(bq, bk, bv, bqkv);

    embed_ln_kernel<<<MTOK, blk, 0, stream>>>(ids, wemb, pemb, emb_g, emb_b, h0, h0_bf);

    for (int pass = 0; pass < 2; ++pass) {
        hipMemcpyAsync(h, h0, MD * 4, hipMemcpyDeviceToDevice, stream);
        hipMemcpyAsync(h_bf, h0_bf, MD * 2, hipMemcpyDeviceToDevice, stream);
        for (int l = 0; l < LAYERS; ++l) {
            const u16* WqkvT_l = WqkvT + (size_t)l * QKVLD * DIM;
            const u16* WoT_l   = WoT   + (size_t)l * DIM * DIM;
            const u16* WiT_l   = WiT   + (size_t)l * FFDIM * DIM;
            const u16* Wo2T_l  = Wo2T  + (size_t)l * DIM * FFDIM;
            const float* bqkv_l = bqkv + (size_t)l * QKVLD;
            const float* bo_l  = bo  + (size_t)l * DIM;
            const float* bi_l  = bi  + (size_t)l * FFDIM;
            const float* bo2_l = bo2 + (size_t)l * DIM;
            const float* g1_l  = g1  + (size_t)l * DIM;
            const float* b1_l  = b1  + (size_t)l * DIM;
            const float* g2_l  = g2  + (size_t)l * DIM;
            const float* b2_l  = b2  + (size_t)l * DIM;

            if (pass == 0) {
                gemm_qkv<0><<<dim3(QKVLD / 128, MTOK / 128), blk, 0, stream>>>(
                    h_bf, WqkvT_l, bqkv_l, qkv_bf, vT,
                    nullptr, nullptr, nullptr, nullptr, nullptr, l);
            } else {
                lora_t_kernel<<<dim3(MTOK / 64, 2), blk, 0, stream>>>(h, qA, vA, task, l, tq, tv);
                gemm_qkv<1><<<dim3(QKVLD / 128, MTOK / 128), blk, 0, stream>>>(
                    h_bf, WqkvT_l, bqkv_l, qkv_bf, vT,
                    tq, tv, qB, vB, task, l);
            }
            attn_fused<<<dim3(SEQ / 64, ZB), blk, 0, stream>>>(qkv_bf, vT, mask, o_bf);
            gemm_mfma<64, 128, 0, 0><<<dim3(DIM / 128, MTOK / 64), blk, 0, stream>>>(
                o_bf, DIM, WoT_l, DIM, bo_l, h2, nullptr, DIM, DIM);
            add_ln_kernel<<<MTOK, blk, 0, stream>>>(h, h2, g1_l, b1_l, h_bf);
            gemm_mfma<128, 128, 1, 1><<<dim3(FFDIM / 128, MTOK / 128), blk, 0, stream>>>(
                h_bf, DIM, WiT_l, DIM, bi_l, nullptr, ffb_bf, FFDIM, DIM);
            gemm_mfma<64, 128, 0, 0><<<dim3(DIM / 128, MTOK / 64), blk, 0, stream>>>(
                ffb_bf, FFDIM, Wo2T_l, FFDIM, bo2_l, h2, nullptr, DIM, FFDIM);
            add_ln_kernel<<<MTOK, blk, 0, stream>>>(h, h2, g2_l, b2_l, h_bf);
        }
        if (pass == 0) {
            head1_kernel<0><<<dim3(12, BATCH), blk, 0, stream>>>(h, rW1, rb1, nullptr, y1);
            router_fin<<<BATCH, blk, 0, stream>>>(y1, rW2, rb2, temp, out, task);
        } else {
            head1_kernel<1><<<dim3(12, BATCH), blk, 0, stream>>>(h, cW1, cb1, task, y1);
            cls_fin<<<BATCH, blk, 0, stream>>>(y1, cW2, cb2, task, out + BATCH * TASKS);
        }
    }
}

// Round 5
// 3684.444 us; speedup vs baseline: 4.3434x; 1.1818x over previous
//
#include <hip/hip_runtime.h>
#include <math.h>

#define DIM 768
#define LAYERS 12
#define NH 12
#define HDIM 64
#define FFDIM 3072
#define SEQ 256
#define BATCH 8
#define MTOK (BATCH*SEQ)   // 2048
#define TASKS 3
#define LRANK 16
#define LORA_SC 2.0f
#define QKVLD 2304
#define ZB (BATCH*NH)      // 96

typedef unsigned short u16;
typedef __attribute__((ext_vector_type(8))) short short8;
typedef __attribute__((ext_vector_type(4))) float floatx4;
typedef __attribute__((ext_vector_type(4))) unsigned short u16x4;

__device__ __forceinline__ u16 f2bf(float f) {
    unsigned int u = __float_as_uint(f);
    u = (u + 0x7fff + ((u >> 16) & 1)) >> 16;
    return (u16)u;
}

__device__ __forceinline__ float geluf(float x) {
    float u = 0.7978845608028654f * (x + 0.044715f * x * x * x);
    u = fminf(fmaxf(u, -15.f), 15.f);
    float e = __expf(2.f * u);
    float th = (e - 1.f) / (e + 1.f);
    return 0.5f * x * (1.f + th);
}

__device__ __forceinline__ float block_sum256(float v, volatile float* sb4) {
    #pragma unroll
    for (int o = 32; o; o >>= 1) v += __shfl_down(v, o);
    int w = threadIdx.x >> 6;
    if ((threadIdx.x & 63) == 0) sb4[w] = v;
    __syncthreads();
    float total = sb4[0] + sb4[1] + sb4[2] + sb4[3];
    __syncthreads();
    return total;
}

// XCD-aware bijective block swizzle (nwg divisible by 8 at all call sites)
__device__ __forceinline__ void xcd_map(int* bx, int* by) {
    int gx = gridDim.x;
    int nwg = gx * gridDim.y;
    int orig = blockIdx.y * gx + blockIdx.x;
    int swz = (orig & 7) * (nwg >> 3) + (orig >> 3);
    *bx = swz % gx; *by = swz / gx;
}

// ============ weight transpose fp32 [K][N] -> bf16 [row_off+N][K], 64x64 ============
__global__ __launch_bounds__(256) void w_transpose64(
    const float* __restrict__ src, size_t src_ls,
    u16* __restrict__ dst, size_t dst_ls, int N, int dstld, int row_off) {
    __shared__ float tile[64][65];
    int l = blockIdx.z;
    int k0 = blockIdx.y * 64, n0 = blockIdx.x * 64;
    int t = threadIdx.x;
    int r = t >> 4, c4 = (t & 15) * 4;
    const float* s = src + (size_t)l * src_ls + (size_t)k0 * N + n0;
    #pragma unroll
    for (int i = 0; i < 4; ++i) {
        float4 v = *(const float4*)&s[(size_t)(r + i * 16) * N + c4];
        tile[r + i * 16][c4 + 0] = v.x; tile[r + i * 16][c4 + 1] = v.y;
        tile[r + i * 16][c4 + 2] = v.z; tile[r + i * 16][c4 + 3] = v.w;
    }
    __syncthreads();
    u16* d = dst + (size_t)l * dst_ls;
    #pragma unroll
    for (int i = 0; i < 4; ++i) {
        int n = r + i * 16;
        u16x4 o;
        o[0] = f2bf(tile[c4 + 0][n]); o[1] = f2bf(tile[c4 + 1][n]);
        o[2] = f2bf(tile[c4 + 2][n]); o[3] = f2bf(tile[c4 + 3][n]);
        *(u16x4*)&d[(size_t)(row_off + n0 + n) * dstld + k0 + c4] = o;
    }
}

__global__ __launch_bounds__(256) void build_bqkv(
    const float* __restrict__ bq, const float* __restrict__ bk,
    const float* __restrict__ bv, float* __restrict__ bqkv) {
    int l = blockIdx.x;
    for (int i = threadIdx.x; i < QKVLD; i += 256) {
        float v = i < DIM ? bq[l * DIM + i]
                : (i < 2 * DIM ? bk[l * DIM + i - DIM] : bv[l * DIM + i - 2 * DIM]);
        bqkv[(size_t)l * QKVLD + i] = v;
    }
}

// ============ embedding + LN (fp32 + bf16 out) ============
__global__ __launch_bounds__(256) void embed_ln_kernel(
    const int* __restrict__ ids, const float* __restrict__ wemb,
    const float* __restrict__ pemb, const float* __restrict__ g,
    const float* __restrict__ bb, float* __restrict__ out, u16* __restrict__ out_bf) {
    __shared__ float sb[4];
    int m = blockIdx.x;
    int s = m & (SEQ - 1);
    int id = ids[m];
    int t = threadIdx.x;
    float x[3];
    float sum = 0.f;
    #pragma unroll
    for (int j = 0; j < 3; ++j) {
        int d = t + j * 256;
        x[j] = wemb[(size_t)id * DIM + d] + pemb[(size_t)(s + 2) * DIM + d];
        sum += x[j];
    }
    float mean = block_sum256(sum, sb) * (1.0f / DIM);
    float vs = 0.f;
    #pragma unroll
    for (int j = 0; j < 3; ++j) { float c = x[j] - mean; vs += c * c; }
    float var = block_sum256(vs, sb) * (1.0f / DIM);
    float rstd = rsqrtf(var + 1e-5f);
    #pragma unroll
    for (int j = 0; j < 3; ++j) {
        int d = t + j * 256;
        float r = (x[j] - mean) * rstd * g[d] + bb[d];
        out[(size_t)m * DIM + d] = r;
        out_bf[(size_t)m * DIM + d] = f2bf(r);
    }
}

// ============ residual add + LN in place, + bf16 out ============
__global__ __launch_bounds__(256) void add_ln_kernel(
    float* __restrict__ h, const float* __restrict__ proj,
    const float* __restrict__ g, const float* __restrict__ bb, u16* __restrict__ h_bf) {
    __shared__ float sb[4];
    int m = blockIdx.x;
    int t = threadIdx.x;
    float x[3];
    float sum = 0.f;
    #pragma unroll
    for (int j = 0; j < 3; ++j) {
        int d = t + j * 256;
        x[j] = h[(size_t)m * DIM + d] + proj[(size_t)m * DIM + d];
        sum += x[j];
    }
    float mean = block_sum256(sum, sb) * (1.0f / DIM);
    float vs = 0.f;
    #pragma unroll
    for (int j = 0; j < 3; ++j) { float c = x[j] - mean; vs += c * c; }
    float var = block_sum256(vs, sb) * (1.0f / DIM);
    float rstd = rsqrtf(var + 1e-5f);
    #pragma unroll
    for (int j = 0; j < 3; ++j) {
        int d = t + j * 256;
        float r = (x[j] - mean) * rstd * g[d] + bb[d];
        h[(size_t)m * DIM + d] = r;
        h_bf[(size_t)m * DIM + d] = f2bf(r);
    }
}

// ============ MFMA GEMM core (double-buffered, counted vmcnt) ============
template<int ROWS>
__device__ __forceinline__ void stage_tile(const u16* srcbase, int ldk,
                                           u16* ldsbase, int wave, int lane) {
    int rin = lane >> 3, slot = lane & 7;
    #pragma unroll
    for (int c0 = 0; c0 < ROWS / 8; c0 += 4) {
        int c = c0 + wave;
        int r = c * 8 + rin;
        int scol = ((slot ^ (r & 7)) << 3);
        const u16* src = srcbase + (size_t)r * ldk + scol;
        __builtin_amdgcn_global_load_lds(
            (const __attribute__((address_space(1))) unsigned int*)src,
            (__attribute__((address_space(3))) unsigned int*)(ldsbase + (size_t)c * 512 + lane * 8),
            16, 0, 0);
    }
}

__device__ __forceinline__ short8 frag_read(const u16* ldsbase, int r, int s) {
    return *(const short8*)(ldsbase + r * 64 + (((s ^ (r & 7)) << 3)));
}

// K/64 must be EVEN at all call sites (K=768 -> 12, K=3072 -> 48).
template<int BM, int BN>
__device__ __forceinline__ void gemm_core(
    const u16* __restrict__ A, int lda, const u16* __restrict__ B, int ldb,
    int K, int m0, int n0, u16* lds, floatx4 (&acc)[BM / 32][BN / 32]) {
    constexpr int TILE = (BM + BN) * 64;
    constexpr int NL = BM / 32 + BN / 32;   // per-thread gload_lds per tile
    u16* buf0 = lds;
    u16* buf1 = lds + TILE;
    int t = threadIdx.x, lane = t & 63, wave = t >> 6;
    int wr = wave >> 1, wc = wave & 1;
    constexpr int FM = BM / 32, FN = BN / 32;
    int wm0 = wr * (BM / 2), wn0 = wc * (BN / 2);
    #pragma unroll
    for (int i = 0; i < FM; ++i)
        #pragma unroll
        for (int j = 0; j < FN; ++j)
            acc[i][j] = (floatx4){0.f, 0.f, 0.f, 0.f};
    int lr = lane & 15, kg = lane >> 4;
    const u16* Abase = A + (size_t)m0 * lda;
    const u16* Bbase = B + (size_t)n0 * ldb;

    auto stage = [&](u16* dst, int k0) {
        stage_tile<BM>(Abase + k0, lda, dst, wave, lane);
        stage_tile<BN>(Bbase + k0, ldb, dst + BM * 64, wave, lane);
    };
    auto compute = [&](const u16* buf) {
        const u16* As = buf;
        const u16* Bs = buf + BM * 64;
        #pragma unroll
        for (int kk = 0; kk < 2; ++kk) {
            short8 af[FM], bfr[FN];
            #pragma unroll
            for (int mi = 0; mi < FM; ++mi)
                af[mi] = frag_read(As, wm0 + mi * 16 + lr, kk * 4 + kg);
            #pragma unroll
            for (int ni = 0; ni < FN; ++ni)
                bfr[ni] = frag_read(Bs, wn0 + ni * 16 + lr, kk * 4 + kg);
            #pragma unroll
            for (int mi = 0; mi < FM; ++mi)
                #pragma unroll
                for (int ni = 0; ni < FN; ++ni)
                    acc[mi][ni] = __builtin_amdgcn_mfma_f32_16x16x32_bf16(
                        af[mi], bfr[ni], acc[mi][ni], 0, 0, 0);
        }
    };

    int nt = K / 64;
    stage(buf0, 0);
    for (int ti = 0; ti < nt; ti += 2) {
        // prefetch tile ti+1 into buf1; wait only for buf0's loads
        stage(buf1, (ti + 1) * 64);
        asm volatile("s_waitcnt vmcnt(%0)" :: "n"(NL) : "memory");
        __builtin_amdgcn_s_barrier();
        __builtin_amdgcn_sched_barrier(0);
        compute(buf0);
        __builtin_amdgcn_sched_barrier(0);
        __builtin_amdgcn_s_barrier();
        // prefetch tile ti+2 into buf0 (if any); wait only for buf1's loads
        if (ti + 2 < nt) {
            stage(buf0, (ti + 2) * 64);
            asm volatile("s_waitcnt vmcnt(%0)" :: "n"(NL) : "memory");
        } else {
            asm volatile("s_waitcnt vmcnt(0)" ::: "memory");
        }
        __builtin_amdgcn_s_barrier();
        __builtin_amdgcn_sched_barrier(0);
        compute(buf1);
        __builtin_amdgcn_sched_barrier(0);
        __builtin_amdgcn_s_barrier();
    }
}

// ---- standard GEMM kernel ----
template<int BM, int BN, int ACT, int OUTMODE>   // OUTMODE: 0=f32, 1=bf16
__global__ __launch_bounds__(256) void gemm_mfma(
    const u16* __restrict__ A, int lda, const u16* __restrict__ B, int ldb,
    const float* __restrict__ bias, float* __restrict__ Cf, u16* __restrict__ Cb,
    int ldc, int K) {
    __shared__ u16 lds[2 * (BM + BN) * 64];
    constexpr int FM = BM / 32, FN = BN / 32;
    floatx4 acc[FM][FN];
    int bx, by;
    xcd_map(&bx, &by);
    int m0 = by * BM, n0 = bx * BN;
    gemm_core<BM, BN>(A, lda, B, ldb, K, m0, n0, lds, acc);
    int t = threadIdx.x, lane = t & 63, wave = t >> 6;
    int wr = wave >> 1, wc = wave & 1;
    int wm0 = wr * (BM / 2), wn0 = wc * (BN / 2);
    int cr = (lane >> 4) * 4, cc = lane & 15;
    #pragma unroll
    for (int mi = 0; mi < FM; ++mi) {
        #pragma unroll
        for (int ni = 0; ni < FN; ++ni) {
            int col = n0 + wn0 + ni * 16 + cc;
            float bsv = bias ? bias[col] : 0.f;
            #pragma unroll
            for (int j = 0; j < 4; ++j) {
                int row = m0 + wm0 + mi * 16 + cr + j;
                float r = acc[mi][ni][j] + bsv;
                if (ACT == 1) r = geluf(r);
                if (OUTMODE == 0) Cf[(size_t)row * ldc + col] = r;
                else Cb[(size_t)row * ldc + col] = f2bf(r);
            }
        }
    }
}

// ---- QKV GEMM: bias, optional fused LoRA, bf16 out, fused vT scatter ----
template<int LORA>
__global__ __launch_bounds__(256) void gemm_qkv(
    const u16* __restrict__ A, const u16* __restrict__ Bw,
    const float* __restrict__ bias, u16* __restrict__ qkv_bf,
    u16* __restrict__ vT,
    const float* __restrict__ tq, const float* __restrict__ tv,
    const float* __restrict__ qBb, const float* __restrict__ vBb,
    const int* __restrict__ taskp, int layer) {
    __shared__ u16 lds[2 * (128 + 128) * 64];
    floatx4 acc[4][4];
    int bx, by;
    xcd_map(&bx, &by);
    int m0 = by * 128, n0 = bx * 128;
    gemm_core<128, 128>(A, DIM, Bw, DIM, DIM, m0, n0, lds, acc);
    int t = threadIdx.x, lane = t & 63, wave = t >> 6;
    int wr = wave >> 1, wc = wave & 1;
    int wm0 = wr * 64, wn0 = wc * 64;
    int cr = (lane >> 4) * 4, cc = lane & 15;
    const float* tvec = nullptr;
    const float* Bmat = nullptr;
    if (LORA) {
        int tk = taskp[m0 >> 8];
        if (n0 < DIM) {
            tvec = tq;
            Bmat = qBb + ((size_t)tk * LAYERS + layer) * DIM * LRANK;
        } else if (n0 >= 2 * DIM) {
            tvec = tv;
            Bmat = vBb + ((size_t)tk * LAYERS + layer) * DIM * LRANK - (size_t)2 * DIM * LRANK;
        }
    }
    bool vrange = (n0 >= 2 * DIM);
    #pragma unroll
    for (int mi = 0; mi < 4; ++mi) {
        #pragma unroll
        for (int j = 0; j < 4; ++j) {
            int row = m0 + wm0 + mi * 16 + cr + j;
            float4 t0, t1, t2, t3;
            if (LORA && tvec) {
                const float* tp = tvec + (size_t)row * LRANK;
                t0 = *(const float4*)(tp + 0);  t1 = *(const float4*)(tp + 4);
                t2 = *(const float4*)(tp + 8);  t3 = *(const float4*)(tp + 12);
            }
            #pragma unroll
            for (int ni = 0; ni < 4; ++ni) {
                int col = n0 + wn0 + ni * 16 + cc;
                float r = acc[mi][ni][j] + bias[col];
                if (LORA && tvec) {
                    const float* bp = Bmat + (size_t)col * LRANK;
                    float4 b0 = *(const float4*)(bp + 0),  b1 = *(const float4*)(bp + 4);
                    float4 b2 = *(const float4*)(bp + 8),  b3 = *(const float4*)(bp + 12);
                    float d = t0.x * b0.x + t0.y * b0.y + t0.z * b0.z + t0.w * b0.w
                            + t1.x * b1.x + t1.y * b1.y + t1.z * b1.z + t1.w * b1.w
                            + t2.x * b2.x + t2.y * b2.y + t2.z * b2.z + t2.w * b2.w
                            + t3.x * b3.x + t3.y * b3.y + t3.z * b3.z + t3.w * b3.w;
                    r += LORA_SC * d;
                }
                u16 rb = f2bf(r);
                qkv_bf[(size_t)row * QKVLD + col] = rb;
                if (vrange) {
                    int vcol = col - 2 * DIM;
                    int hh = vcol >> 6, dd = vcol & 63;
                    int bb = row >> 8, kpos = row & 255;
                    vT[((size_t)(bb * NH + hh) * HDIM + dd) * SEQ + kpos] = rb;
                }
            }
        }
    }
}

// ============ fused attention ============
__device__ __forceinline__ int lds256_idx(int r, int col) {
    int sub = col >> 6, inner = col & 63;
    return r * 256 + sub * 64 + ((((inner >> 3) ^ (r & 7))) << 3) + (inner & 7);
}
__device__ __forceinline__ short8 frag_read256(const u16* base, int r, int kk, int kg) {
    int col = kk * 32 + kg * 8;
    int sub = col >> 6, slot = (col & 63) >> 3;
    return *(const short8*)(base + r * 256 + sub * 64 + ((slot ^ (r & 7)) << 3));
}

__global__ __launch_bounds__(256) void attn_fused(
    const u16* __restrict__ qkv_bf, const u16* __restrict__ vT,
    const int* __restrict__ mask, u16* __restrict__ o_bf) {
    __shared__ u16 lds[256 * 64 + 64 * 256];
    u16* KV = lds;
    u16* P = lds + 256 * 64;
    int qt = blockIdx.x, z = blockIdx.y;
    int b = z / NH, h = z % NH;
    int t = threadIdx.x, lane = t & 63, w = t >> 6;
    int cc = lane & 15, q4 = lane >> 4;

    float mb[16];
    #pragma unroll
    for (int ni = 0; ni < 16; ++ni)
        mb[ni] = (1.0f - (float)mask[b * SEQ + ni * 16 + cc]) * -1e9f;

    int qrow = b * SEQ + qt * 64 + w * 16 + cc;
    const u16* qp = qkv_bf + (size_t)qrow * QKVLD + h * HDIM + q4 * 8;
    short8 qa0 = *(const short8*)(qp);
    short8 qa1 = *(const short8*)(qp + 32);

    stage_tile<256>(qkv_bf + (size_t)(b * SEQ) * QKVLD + DIM + h * HDIM, QKVLD, KV, w, lane);
    __syncthreads();

    floatx4 s[16];
    #pragma unroll
    for (int ni = 0; ni < 16; ++ni) s[ni] = (floatx4){0.f, 0.f, 0.f, 0.f};
    #pragma unroll
    for (int kk = 0; kk < 2; ++kk) {
        short8 qa = kk == 0 ? qa0 : qa1;
        #pragma unroll
        for (int ni = 0; ni < 16; ++ni) {
            short8 kf = frag_read(KV, ni * 16 + cc, kk * 4 + q4);
            s[ni] = __builtin_amdgcn_mfma_f32_16x16x32_bf16(qa, kf, s[ni], 0, 0, 0);
        }
    }

    float pv[16][4];
    float mrow[4] = {-1e30f, -1e30f, -1e30f, -1e30f};
    #pragma unroll
    for (int ni = 0; ni < 16; ++ni)
        #pragma unroll
        for (int j = 0; j < 4; ++j) {
            float v = s[ni][j] * 0.125f + mb[ni];
            pv[ni][j] = v;
            mrow[j] = fmaxf(mrow[j], v);
        }
    #pragma unroll
    for (int o = 1; o < 16; o <<= 1)
        #pragma unroll
        for (int j = 0; j < 4; ++j) mrow[j] = fmaxf(mrow[j], __shfl_xor(mrow[j], o));
    float srow[4] = {0.f, 0.f, 0.f, 0.f};
    #pragma unroll
    for (int ni = 0; ni < 16; ++ni)
        #pragma unroll
        for (int j = 0; j < 4; ++j) {
            float e = __expf(pv[ni][j] - mrow[j]);
            pv[ni][j] = e;
            srow[j] += e;
        }
    #pragma unroll
    for (int o = 1; o < 16; o <<= 1)
        #pragma unroll
        for (int j = 0; j < 4; ++j) srow[j] += __shfl_xor(srow[j], o);
    float inv[4];
    #pragma unroll
    for (int j = 0; j < 4; ++j) inv[j] = 1.0f / srow[j];

    u16* Pw = P + w * 16 * 256;
    #pragma unroll
    for (int ni = 0; ni < 16; ++ni)
        #pragma unroll
        for (int j = 0; j < 4; ++j)
            Pw[lds256_idx(q4 * 4 + j, ni * 16 + cc)] = f2bf(pv[ni][j] * inv[j]);
    __syncthreads();

    {
        const u16* vz = vT + (size_t)z * HDIM * SEQ;
        int rin = lane >> 3, slot = lane & 7;
        #pragma unroll
        for (int c0 = 0; c0 < 32; c0 += 4) {
            int c = c0 + w;
            int vrow = c * 8 + rin;
            int d = vrow >> 2, sub = vrow & 3;
            const u16* src = vz + d * 256 + sub * 64 + (((slot ^ (d & 7))) << 3);
            __builtin_amdgcn_global_load_lds(
                (const __attribute__((address_space(1))) unsigned int*)src,
                (__attribute__((address_space(3))) unsigned int*)(KV + c * 512 + lane * 8),
                16, 0, 0);
        }
    }
    __syncthreads();

    floatx4 oa[4];
    #pragma unroll
    for (int ni = 0; ni < 4; ++ni) oa[ni] = (floatx4){0.f, 0.f, 0.f, 0.f};
    #pragma unroll
    for (int kk = 0; kk < 8; ++kk) {
        short8 pf = frag_read256(Pw, cc, kk, q4);
        #pragma unroll
        for (int ni = 0; ni < 4; ++ni) {
            short8 vf = frag_read256(KV, ni * 16 + cc, kk, q4);
            oa[ni] = __builtin_amdgcn_mfma_f32_16x16x32_bf16(pf, vf, oa[ni], 0, 0, 0);
        }
    }
    #pragma unroll
    for (int ni = 0; ni < 4; ++ni)
        #pragma unroll
        for (int j = 0; j < 4; ++j) {
            int m = b * SEQ + qt * 64 + w * 16 + q4 * 4 + j;
            o_bf[(size_t)m * DIM + h * HDIM + ni * 16 + cc] = f2bf(oa[ni][j]);
        }
}

// ============ LoRA t-vectors ============
__global__ __launch_bounds__(256) void lora_t_kernel(
    const float* __restrict__ h, const float* __restrict__ qA,
    const float* __restrict__ vA, const int* __restrict__ task,
    int layer, float* __restrict__ tq, float* __restrict__ tv) {
    int which = blockIdx.y;
    const float* Ab = which ? vA : qA;
    float* tout = which ? tv : tq;
    int m0 = blockIdx.x * 64;
    int tk = task[m0 >> 8];
    const float* Ap = Ab + ((size_t)tk * LAYERS + layer) * LRANK * DIM;
    int t = threadIdx.x;
    int row = t & 63, rb = t >> 6;
    float s[4] = {0.f, 0.f, 0.f, 0.f};
    const float* hrow = h + (size_t)(m0 + row) * DIM;
    for (int d = 0; d < DIM; d += 4) {
        float4 hv = *(const float4*)&hrow[d];
        #pragma unroll
        for (int i = 0; i < 4; ++i) {
            float4 av = *(const float4*)&Ap[(size_t)(rb + i * 4) * DIM + d];
            s[i] += hv.x * av.x + hv.y * av.y + hv.z * av.z + hv.w * av.w;
        }
    }
    #pragma unroll
    for (int i = 0; i < 4; ++i)
        tout[(size_t)(m0 + row) * LRANK + rb + i * 4] = s[i];
}

// ============ heads: stage 1 (parallel matvec y1 = act(cls@W1+b1)) ============
template<int TANH>
__global__ __launch_bounds__(256) void head1_kernel(
    const float* __restrict__ h, const float* __restrict__ W1base,
    const float* __restrict__ b1base, const int* __restrict__ taskp,
    float* __restrict__ y1) {
    int b = blockIdx.y;
    int c0 = blockIdx.x * 64;
    int tk = taskp ? taskp[b] : 0;
    const float* W1 = W1base + (size_t)tk * DIM * DIM;
    const float* b1 = b1base + (size_t)tk * DIM;
    __shared__ float cls[DIM];
    __shared__ float part[4][64];
    int t = threadIdx.x;
    for (int j = t; j < DIM; j += 256) cls[j] = h[(size_t)(b * SEQ) * DIM + j];
    __syncthreads();
    int col = c0 + (t & 63);
    int seg = t >> 6;
    float s = 0.f;
    #pragma unroll 4
    for (int d = seg * 192; d < seg * 192 + 192; ++d)
        s += cls[d] * W1[(size_t)d * DIM + col];
    part[seg][t & 63] = s;
    __syncthreads();
    if (t < 64) {
        float r = part[0][t] + part[1][t] + part[2][t] + part[3][t] + b1[c0 + t];
        y1[(size_t)b * DIM + c0 + t] = TANH ? tanhf(r) : fmaxf(r, 0.f);
    }
}

// ============ router finalize ============
__global__ __launch_bounds__(256) void router_fin(
    const float* __restrict__ y1, const float* __restrict__ W2,
    const float* __restrict__ b2, const float* __restrict__ temp,
    float* __restrict__ out_logits, int* __restrict__ task) {
    int b = blockIdx.x;
    int t = threadIdx.x;
    __shared__ float red[3][4];
    float p[3] = {0.f, 0.f, 0.f};
    #pragma unroll
    for (int j = 0; j < 3; ++j) {
        int col = t + j * 256;
        float y = y1[(size_t)b * DIM + col];
        p[0] += y * W2[col * 3 + 0];
        p[1] += y * W2[col * 3 + 1];
        p[2] += y * W2[col * 3 + 2];
    }
    #pragma unroll
    for (int o = 32; o; o >>= 1) {
        p[0] += __shfl_down(p[0], o);
        p[1] += __shfl_down(p[1], o);
        p[2] += __shfl_down(p[2], o);
    }
    int w = t >> 6;
    if ((t & 63) == 0) { red[0][w] = p[0]; red[1][w] = p[1]; red[2][w] = p[2]; }
    __syncthreads();
    if (t == 0) {
        float tt = fmaxf(temp[0], 0.05f);
        float l[3];
        #pragma unroll
        for (int c = 0; c < 3; ++c) {
            l[c] = (red[c][0] + red[c][1] + red[c][2] + red[c][3] + b2[c]) / tt;
            out_logits[b * 3 + c] = l[c];
        }
        int bt = 0; float bv = l[0];
        if (l[1] > bv) { bv = l[1]; bt = 1; }
        if (l[2] > bv) { bv = l[2]; bt = 2; }
        task[b] = bt;
    }
}

// ============ classifier finalize ============
__global__ __launch_bounds__(256) void cls_fin(
    const float* __restrict__ y1, const float* __restrict__ cW2,
    const float* __restrict__ cb2, const int* __restrict__ task,
    float* __restrict__ out) {
    int b = blockIdx.x;
    int t = threadIdx.x;
    int tk = task[b];
    const float* W2 = cW2 + (size_t)tk * DIM * 2;
    const float* b2 = cb2 + tk * 2;
    __shared__ float red[2][4];
    float p[2] = {0.f, 0.f};
    #pragma unroll
    for (int j = 0; j < 3; ++j) {
        int col = t + j * 256;
        float y = y1[(size_t)b * DIM + col];
        p[0] += y * W2[col * 2 + 0];
        p[1] += y * W2[col * 2 + 1];
    }
    #pragma unroll
    for (int o = 32; o; o >>= 1) {
        p[0] += __shfl_down(p[0], o);
        p[1] += __shfl_down(p[1], o);
    }
    int w = t >> 6;
    if ((t & 63) == 0) { red[0][w] = p[0]; red[1][w] = p[1]; }
    __syncthreads();
    if (t == 0) {
        #pragma unroll
        for (int c = 0; c < 2; ++c)
            out[b * 2 + c] = red[c][0] + red[c][1] + red[c][2] + red[c][3] + b2[c];
    }
}

extern "C" void kernel_launch(void* const* d_in, const int* in_sizes, int n_in,
                              void* d_out, int out_size, void* d_ws, size_t ws_size,
                              hipStream_t stream) {
    (void)in_sizes; (void)n_in; (void)out_size; (void)ws_size;
    const int*   ids   = (const int*)d_in[0];
    const int*   mask  = (const int*)d_in[1];
    const float* wemb  = (const float*)d_in[2];
    const float* pemb  = (const float*)d_in[3];
    const float* emb_g = (const float*)d_in[4];
    const float* emb_b = (const float*)d_in[5];
    const float* Wq    = (const float*)d_in[6];
    const float* Wk    = (const float*)d_in[7];
    const float* Wv    = (const float*)d_in[8];
    const float* Wo    = (const float*)d_in[9];
    const float* Wi    = (const float*)d_in[10];
    const float* Wo2   = (const float*)d_in[11];
    const float* bq    = (const float*)d_in[12];
    const float* bk    = (const float*)d_in[13];
    const float* bv    = (const float*)d_in[14];
    const float* bo    = (const float*)d_in[15];
    const float* bi    = (const float*)d_in[16];
    const float* bo2   = (const float*)d_in[17];
    const float* g1    = (const float*)d_in[18];
    const float* b1    = (const float*)d_in[19];
    const float* g2    = (const float*)d_in[20];
    const float* b2    = (const float*)d_in[21];
    const float* rW1   = (const float*)d_in[22];
    const float* rb1   = (const float*)d_in[23];
    const float* rW2   = (const float*)d_in[24];
    const float* rb2   = (const float*)d_in[25];
    const float* temp  = (const float*)d_in[26];
    const float* qA    = (const float*)d_in[27];
    const float* qB    = (const float*)d_in[28];
    const float* vA    = (const float*)d_in[29];
    const float* vB    = (const float*)d_in[30];
    const float* cW1   = (const float*)d_in[31];
    const float* cb1   = (const float*)d_in[32];
    const float* cW2   = (const float*)d_in[33];
    const float* cb2   = (const float*)d_in[34];
    float* out = (float*)d_out;

    const size_t MD = (size_t)MTOK * DIM;
    char* p = (char*)d_ws;
    auto alloc = [&](size_t bytes) { char* r = p; p += (bytes + 255) & ~(size_t)255; return r; };
    float* h      = (float*)alloc(MD * 4);
    float* h2     = (float*)alloc(MD * 4);
    u16* h_bf   = (u16*)alloc(MD * 2);
    u16* o_bf   = (u16*)alloc(MD * 2);
    u16* qkv_bf = (u16*)alloc((size_t)MTOK * QKVLD * 2);
    u16* ffb_bf = (u16*)alloc((size_t)MTOK * FFDIM * 2);
    u16* vT     = (u16*)alloc((size_t)ZB * HDIM * SEQ * 2);
    float* tq   = (float*)alloc((size_t)MTOK * LRANK * 4);
    float* tv   = (float*)alloc((size_t)MTOK * LRANK * 4);
    float* bqkv = (float*)alloc((size_t)LAYERS * QKVLD * 4);
    float* y1   = (float*)alloc((size_t)BATCH * DIM * 4);
    int* task   = (int*)alloc(256);
    u16* WqkvT  = (u16*)alloc((size_t)LAYERS * QKVLD * DIM * 2);
    u16* WoT    = (u16*)alloc((size_t)LAYERS * DIM * DIM * 2);
    u16* WiT    = (u16*)alloc((size_t)LAYERS * FFDIM * DIM * 2);
    u16* Wo2T   = (u16*)alloc((size_t)LAYERS * DIM * FFDIM * 2);

    dim3 blk(256);
    // --- weight prep (bf16, [N][K]) ---
    w_transpose64<<<dim3(12, 12, LAYERS), blk, 0, stream>>>(Wq, (size_t)DIM * DIM, WqkvT, (size_t)QKVLD * DIM, DIM, DIM, 0);
    w_transpose64<<<dim3(12, 12, LAYERS), blk, 0, stream>>>(Wk, (size_t)DIM * DIM, WqkvT, (size_t)QKVLD * DIM, DIM, DIM, DIM);
    w_transpose64<<<dim3(12, 12, LAYERS), blk, 0, stream>>>(Wv, (size_t)DIM * DIM, WqkvT, (size_t)QKVLD * DIM, DIM, DIM, 2 * DIM);
    w_transpose64<<<dim3(12, 12, LAYERS), blk, 0, stream>>>(Wo, (size_t)DIM * DIM, WoT, (size_t)DIM * DIM, DIM, DIM, 0);
    w_transpose64<<<dim3(48, 12, LAYERS), blk, 0, stream>>>(Wi, (size_t)DIM * FFDIM, WiT, (size_t)FFDIM * DIM, FFDIM, DIM, 0);
    w_transpose64<<<dim3(12, 48, LAYERS), blk, 0, stream>>>(Wo2, (size_t)FFDIM * DIM, Wo2T, (size_t)DIM * FFDIM, DIM, FFDIM, 0);
    build_bqkv<<<LAYERS, blk, 0, stream>>>(bq, bk, bv, bqkv);

    for (int pass = 0; pass < 2; ++pass) {
        embed_ln_kernel<<<MTOK, blk, 0, stream>>>(ids, wemb, pemb, emb_g, emb_b, h, h_bf);
        for (int l = 0; l < LAYERS; ++l) {
            const u16* WqkvT_l = WqkvT + (size_t)l * QKVLD * DIM;
            const u16* WoT_l   = WoT   + (size_t)l * DIM * DIM;
            const u16* WiT_l   = WiT   + (size_t)l * FFDIM * DIM;
            const u16* Wo2T_l  = Wo2T  + (size_t)l * DIM * FFDIM;
            const float* bqkv_l = bqkv + (size_t)l * QKVLD;
            const float* bo_l  = bo  + (size_t)l * DIM;
            const float* bi_l  = bi  + (size_t)l * FFDIM;
            const float* bo2_l = bo2 + (size_t)l * DIM;
            const float* g1_l  = g1  + (size_t)l * DIM;
            const float* b1_l  = b1  + (size_t)l * DIM;
            const float* g2_l  = g2  + (size_t)l * DIM;
            const float* b2_l  = b2  + (size_t)l * DIM;

            if (pass == 0) {
                gemm_qkv<0><<<dim3(QKVLD / 128, MTOK / 128), blk, 0, stream>>>(
                    h_bf, WqkvT_l, bqkv_l, qkv_bf, vT,
                    nullptr, nullptr, nullptr, nullptr, nullptr, l);
            } else {
                lora_t_kernel<<<dim3(MTOK / 64, 2), blk, 0, stream>>>(h, qA, vA, task, l, tq, tv);
                gemm_qkv<1><<<dim3(QKVLD / 128, MTOK / 128), blk, 0, stream>>>(
                    h_bf, WqkvT_l, bqkv_l, qkv_bf, vT,
                    tq, tv, qB, vB, task, l);
            }
            attn_fused<<<dim3(SEQ / 64, ZB), blk, 0, stream>>>(qkv_bf, vT, mask, o_bf);
            gemm_mfma<64, 128, 0, 0><<<dim3(DIM / 128, MTOK / 64), blk, 0, stream>>>(
                o_bf, DIM, WoT_l, DIM, bo_l, h2, nullptr, DIM, DIM);
            add_ln_kernel<<<MTOK, blk, 0, stream>>>(h, h2, g1_l, b1_l, h_bf);
            gemm_mfma<128, 128, 1, 1><<<dim3(FFDIM / 128, MTOK / 128), blk, 0, stream>>>(
                h_bf, DIM, WiT_l, DIM, bi_l, nullptr, ffb_bf, FFDIM, DIM);
            gemm_mfma<64, 128, 0, 0><<<dim3(DIM / 128, MTOK / 64), blk, 0, stream>>>(
                ffb_bf, FFDIM, Wo2T_l, FFDIM, bo2_l, h2, nullptr, DIM, FFDIM);
            add_ln_kernel<<<MTOK, blk, 0, stream>>>(h, h2, g2_l, b2_l, h_bf);
        }
        if (pass == 0) {
            head1_kernel<0><<<dim3(12, BATCH), blk, 0, stream>>>(h, rW1, rb1, nullptr, y1);
            router_fin<<<BATCH, blk, 0, stream>>>(y1, rW2, rb2, temp, out, task);
        } else {
            head1_kernel<1><<<dim3(12, BATCH), blk, 0, stream>>>(h, cW1, cb1, task, y1);
            cls_fin<<<BATCH, blk, 0, stream>>>(y1, cW2, cb2, task, out + BATCH * TASKS);
        }
    }
}